// Round 1
// baseline (535.789 us; speedup 1.0000x reference)
//
#include <hip/hip_runtime.h>

#define DEVFN __device__ __forceinline__

typedef float    floatx4 __attribute__((ext_vector_type(4)));
typedef _Float16 half8   __attribute__((ext_vector_type(8)));
typedef _Float16 half4v  __attribute__((ext_vector_type(4)));

#define MFMA16H(a, b, c) __builtin_amdgcn_mfma_f32_16x16x32_f16((a), (b), (c), 0, 0, 0)

DEVFN void async16(void* lds, const void* g) {
  __builtin_amdgcn_global_load_lds(
      (const __attribute__((address_space(1))) unsigned int*)g,
      (__attribute__((address_space(3))) unsigned int*)lds, 16, 0, 0);
}
DEVFN half8 ld8h(const _Float16* p) { return *(const half8*)p; }

// ---------------------------------------------------------------------------
// prep: x -> fp16 hi/lo split; Wq,Wk,Wv,Wo -> fp16; rope tables (fp64) folded
// ---------------------------------------------------------------------------
__global__ __launch_bounds__(256) void cvt_prep(
    const float4* __restrict__ x, const float4* __restrict__ wq,
    const float4* __restrict__ wk, const float4* __restrict__ wv,
    const float4* __restrict__ wo,
    half4v* __restrict__ xh, half4v* __restrict__ xl,
    half4v* __restrict__ qo, half4v* __restrict__ ko,
    half4v* __restrict__ vo, half4v* __restrict__ oo,
    float* __restrict__ cosT, float* __restrict__ sinT) {
  int i = blockIdx.x * 256 + threadIdx.x;  // grid covers 2097152 float4 of x
  {
    float4 v = x[i];
    half4v h = {(_Float16)v.x, (_Float16)v.y, (_Float16)v.z, (_Float16)v.w};
    half4v l = {(_Float16)(v.x - (float)h.x), (_Float16)(v.y - (float)h.y),
                (_Float16)(v.z - (float)h.z), (_Float16)(v.w - (float)h.w)};
    xh[i] = h;
    xl[i] = l;
  }
  if (i < 1048576) {
    float4 v = wq[i];
    qo[i] = (half4v){(_Float16)v.x, (_Float16)v.y, (_Float16)v.z, (_Float16)v.w};
    v = wk[i];
    ko[i] = (half4v){(_Float16)v.x, (_Float16)v.y, (_Float16)v.z, (_Float16)v.w};
    v = wv[i];
    vo[i] = (half4v){(_Float16)v.x, (_Float16)v.y, (_Float16)v.z, (_Float16)v.w};
    v = wo[i];
    oo[i] = (half4v){(_Float16)v.x, (_Float16)v.y, (_Float16)v.z, (_Float16)v.w};
  }
  if (i < 131072) {  // rope tables: t = i>>6, d = i&63
    int t = i >> 6, d = i & 63;
    double theta = exp(-((double)(2 * d) / 128.0) * log(10000.0));
    double ang = (double)t * theta;
    cosT[i] = (float)cos(ang);
    sinT[i] = (float)sin(ang);
  }
}

// ---------------------------------------------------------------------------
// Fused QKV projection, fp16. 128x128 tile, BK=32, 512 threads (8 waves,
// each wave owns one 16-row granule x all 128 cols). Pipelined schedule:
// 3x40KB LDS k-tile buffers, 2-deep prefetch via global_load_lds, 4 phases
// per k-tile (10 MFMA each) with raw s_barrier pairs + setprio(1) around
// MFMA clusters, and COUNTED s_waitcnt vmcnt(5) at tile boundaries (loads
// stay in flight across barriers; never drained to 0 in steady state).
// Q,K = 2-pass (x split exact, W fp16-rounded), V = 1-pass.
// Epilogue: RoPE fp32; Q split-fp16 (hi+lo), K,V single fp16 at [B,NH,T,HD],
// staged through dead K-loop LDS so global stores are contiguous 16 B/lane.
// ---------------------------------------------------------------------------
__global__ __launch_bounds__(512, 2) void gemm_qkv_f16(
    const _Float16* __restrict__ xhp, const _Float16* __restrict__ xlp,
    const _Float16* __restrict__ wq, const _Float16* __restrict__ wk,
    const _Float16* __restrict__ wv,
    const float* __restrict__ cosT, const float* __restrict__ sinT,
    const float* __restrict__ sqk,
    _Float16* __restrict__ qhi, _Float16* __restrict__ qlo,
    _Float16* __restrict__ khi, _Float16* __restrict__ vo) {
  constexpr int Kd = 2048, NT = 64;
  const int n0 = blockIdx.x * 128, m0 = blockIdx.y * 128;
  const int tid = threadIdx.x, w = tid >> 6, lane = tid & 63;
  const int quad = lane >> 4, l16 = lane & 15;

  // 3 k-tile buffers x 20480 halves (Xh,Xl,Wq,Wk,Wv = 5 x 4096) = 120 KB
  __shared__ __align__(16) _Float16 smem[61440];
#define BUF(b) (smem + (b) * 20480)

  floatx4 accQ[8], accK[8], accV[8];
#pragma unroll
  for (int j = 0; j < 8; j++) {
    accQ[j] = (floatx4){0.f, 0.f, 0.f, 0.f};
    accK[j] = (floatx4){0.f, 0.f, 0.f, 0.f};
    accV[j] = (floatx4){0.f, 0.f, 0.f, 0.f};
  }

  // wave w stages granule w of each sub-buffer (5 global_load_lds / thread /
  // k-tile); granule = [16 rows][32 k] halves, lane-linear (conflict-free)
  const size_t xoff = (size_t)(m0 + w * 16 + l16) * Kd + quad * 8;
  const size_t woff = (size_t)(n0 + w * 16 + l16) * Kd + quad * 8;

  // ---- prologue: tile 0 -> buf0, tile 1 -> buf1 (10 loads outstanding) ----
  async16(BUF(0) + w * 512,         xhp + xoff);
  async16(BUF(0) + 4096 + w * 512,  xlp + xoff);
  async16(BUF(0) + 8192 + w * 512,  wq + woff);
  async16(BUF(0) + 12288 + w * 512, wk + woff);
  async16(BUF(0) + 16384 + w * 512, wv + woff);
  async16(BUF(1) + w * 512,         xhp + xoff + 32);
  async16(BUF(1) + 4096 + w * 512,  xlp + xoff + 32);
  async16(BUF(1) + 8192 + w * 512,  wq + woff + 32);
  async16(BUF(1) + 12288 + w * 512, wk + woff + 32);
  async16(BUF(1) + 16384 + w * 512, wv + woff + 32);
  asm volatile("s_waitcnt vmcnt(5)" ::: "memory");  // tile 0 landed
  __builtin_amdgcn_s_barrier();

// one phase: 6 b-frag ds_reads (+ phase-0 a-frags) + stage issue, barrier,
// lgkm drain, prio-boosted 10-MFMA cluster (j-pair J0,J0+1 of Q,K,V)
#define QKV_PHASE(J0, STAGE)                                        \
  {                                                                 \
    half8 bq0 = ld8h(qs_ + (J0) * 512 + lane * 8);                  \
    half8 bq1 = ld8h(qs_ + ((J0) + 1) * 512 + lane * 8);            \
    half8 bk0 = ld8h(ks_ + (J0) * 512 + lane * 8);                  \
    half8 bk1 = ld8h(ks_ + ((J0) + 1) * 512 + lane * 8);            \
    half8 bv0 = ld8h(vs_ + (J0) * 512 + lane * 8);                  \
    half8 bv1 = ld8h(vs_ + ((J0) + 1) * 512 + lane * 8);            \
    STAGE;                                                          \
    __builtin_amdgcn_s_barrier();                                   \
    asm volatile("s_waitcnt lgkmcnt(0)");                           \
    __builtin_amdgcn_sched_barrier(0);                              \
    __builtin_amdgcn_s_setprio(1);                                  \
    accQ[(J0)] = MFMA16H(ah, bq0, accQ[(J0)]);                      \
    accQ[(J0) + 1] = MFMA16H(ah, bq1, accQ[(J0) + 1]);              \
    accK[(J0)] = MFMA16H(ah, bk0, accK[(J0)]);                      \
    accK[(J0) + 1] = MFMA16H(ah, bk1, accK[(J0) + 1]);              \
    accV[(J0)] = MFMA16H(ah, bv0, accV[(J0)]);                      \
    accV[(J0) + 1] = MFMA16H(ah, bv1, accV[(J0) + 1]);              \
    accQ[(J0)] = MFMA16H(al, bq0, accQ[(J0)]);                      \
    accQ[(J0) + 1] = MFMA16H(al, bq1, accQ[(J0) + 1]);              \
    accK[(J0)] = MFMA16H(al, bk0, accK[(J0)]);                      \
    accK[(J0) + 1] = MFMA16H(al, bk1, accK[(J0) + 1]);              \
    __builtin_amdgcn_s_setprio(0);                                  \
  }

  int cur = 0;
#pragma unroll 1
  for (int t = 0; t < NT; ++t) {
    const _Float16* xh_ = BUF(cur);
    const _Float16* xl_ = BUF(cur) + 4096;
    const _Float16* qs_ = BUF(cur) + 8192;
    const _Float16* ks_ = BUF(cur) + 12288;
    const _Float16* vs_ = BUF(cur) + 16384;
    int nb = cur - 1;
    if (nb < 0) nb = 2;               // buffer of tile t-1, now free -> t+2
    _Float16* nxt = BUF(nb);
    const bool pre = t < NT - 2;
    const int kpre = (t + 2) * 32;
    half8 ah, al;

    QKV_PHASE(0,
      ah = ld8h(xh_ + w * 512 + lane * 8);
      al = ld8h(xl_ + w * 512 + lane * 8);
      if (pre) {
        async16(nxt + w * 512, xhp + xoff + kpre);
        async16(nxt + 4096 + w * 512, xlp + xoff + kpre);
      }
    );
    __builtin_amdgcn_s_barrier();
    QKV_PHASE(2,
      if (pre) { async16(nxt + 8192 + w * 512, wq + woff + kpre); }
    );
    __builtin_amdgcn_s_barrier();
    QKV_PHASE(4,
      if (pre) { async16(nxt + 12288 + w * 512, wk + woff + kpre); }
    );
    __builtin_amdgcn_s_barrier();
    QKV_PHASE(6,
      if (pre) { async16(nxt + 16384 + w * 512, wv + woff + kpre); }
    );
    // tile boundary: 5 newest outstanding loads are t+2's -> t+1 is landed
    if (pre) {
      asm volatile("s_waitcnt vmcnt(5)" ::: "memory");
    } else {
      asm volatile("s_waitcnt vmcnt(0)" ::: "memory");
    }
    __builtin_amdgcn_s_barrier();
    cur++;
    if (cur == 3) cur = 0;
  }
#undef QKV_PHASE

  __syncthreads();  // K-loop LDS dead; reuse as epilogue staging
  _Float16* stH = smem + w * 2176;           // 16 x 136 halves per wave
  _Float16* stL = smem + 17408 + w * 2176;

  const int h = n0 >> 7;
  const int grow0 = m0 + w * 16;
  const int bb = grow0 >> 11, tt0 = grow0 & 2047;
  const size_t gbase = (((size_t)(bb * 16 + h)) * 2048 + tt0) * 128;

  // ---- Q: RoPE + sqk*sqrt(2048)*sqrt(128), split-fp16 ----
#pragma unroll
  for (int j = 0; j < 4; j++) {
    int d = j * 16 + l16;
    float s1 = sqk[h * 128 + d] * 512.0f;
    float s2 = sqk[h * 128 + d + 64] * 512.0f;
#pragma unroll
    for (int r = 0; r < 4; r++) {
      int tq = tt0 + quad * 4 + r;
      float c = cosT[tq * 64 + d], s = sinT[tq * 64 + d];
      float xr = accQ[j][r], xi = accQ[j + 4][r];
      float o1 = (xr * c - xi * s) * s1;
      float o2 = (xr * s + xi * c) * s2;
      _Float16 h1 = (_Float16)o1, h2 = (_Float16)o2;
      int rl = quad * 4 + r;
      stH[rl * 136 + d] = h1;
      stH[rl * 136 + d + 64] = h2;
      stL[rl * 136 + d] = (_Float16)(o1 - (float)h1);
      stL[rl * 136 + d + 64] = (_Float16)(o2 - (float)h2);
    }
  }
#pragma unroll
  for (int it = 0; it < 4; it++) {
    int pbyte = it * 1024 + lane * 16;
    int rr = pbyte >> 8, cs = (pbyte & 255) >> 1;
    *(half8*)(qhi + gbase + rr * 128 + cs) = ld8h(&stH[rr * 136 + cs]);
    *(half8*)(qlo + gbase + rr * 128 + cs) = ld8h(&stL[rr * 136 + cs]);
  }

  // ---- K: RoPE + sqk*sqrt(2048), single fp16 ----
#pragma unroll
  for (int j = 0; j < 4; j++) {
    int d = j * 16 + l16;
    float s1 = sqk[h * 128 + d] * 45.254834f;
    float s2 = sqk[h * 128 + d + 64] * 45.254834f;
#pragma unroll
    for (int r = 0; r < 4; r++) {
      int tq = tt0 + quad * 4 + r;
      float c = cosT[tq * 64 + d], s = sinT[tq * 64 + d];
      float xr = accK[j][r], xi = accK[j + 4][r];
      int rl = quad * 4 + r;
      stH[rl * 136 + d] = (_Float16)((xr * c - xi * s) * s1);
      stH[rl * 136 + d + 64] = (_Float16)((xr * s + xi * c) * s2);
    }
  }
#pragma unroll
  for (int it = 0; it < 4; it++) {
    int pbyte = it * 1024 + lane * 16;
    int rr = pbyte >> 8, cs = (pbyte & 255) >> 1;
    *(half8*)(khi + gbase + rr * 128 + cs) = ld8h(&stH[rr * 136 + cs]);
  }

  // ---- V: plain fp16 ----
#pragma unroll
  for (int j = 0; j < 8; j++)
#pragma unroll
    for (int r = 0; r < 4; r++)
      stH[(quad * 4 + r) * 136 + j * 16 + l16] = (_Float16)accV[j][r];
#pragma unroll
  for (int it = 0; it < 4; it++) {
    int pbyte = it * 1024 + lane * 16;
    int rr = pbyte >> 8, cs = (pbyte & 255) >> 1;
    *(half8*)(vo + gbase + rr * 128 + cs) = ld8h(&stH[rr * 136 + cs]);
  }
#undef BUF
}

// ---------------------------------------------------------------------------
// transpose V: [BH][T][HD] -> [BH][HD][T] (16-bit payload)
// ---------------------------------------------------------------------------
__global__ __launch_bounds__(256) void transpose_v(
    const unsigned short* __restrict__ v, unsigned short* __restrict__ vt) {
  __shared__ unsigned short tile[32][33];
  int t0 = blockIdx.x * 32, d0 = blockIdx.y * 32, bh = blockIdx.z;
  int tx = threadIdx.x & 31, ty = threadIdx.x >> 5;
  for (int r = ty; r < 32; r += 8)
    tile[r][tx] = v[((size_t)bh * 2048 + t0 + r) * 128 + d0 + tx];
  __syncthreads();
  for (int r = ty; r < 32; r += 8)
    vt[((size_t)bh * 128 + d0 + r) * 2048 + t0 + tx] = tile[tx][r];
}

// ---------------------------------------------------------------------------
// flash attention: block = (bh, 128 q-rows). 4 waves x 32 rows, K-tiles of
// 64. QK^T 2-pass (qh*kh + ql*kh; q split exact, k fp16-rounded), online
// softmax fp32, PV fp16. q split at [BH][T][128], k single fp16;
// v transposed [BH][128][T].
// ---------------------------------------------------------------------------
__global__ __launch_bounds__(256, 2) void flash_attn(
    const _Float16* __restrict__ qhp, const _Float16* __restrict__ qlp,
    const _Float16* __restrict__ khp,
    const _Float16* __restrict__ vtp, _Float16* __restrict__ aout) {
  constexpr int T = 2048, HD = 128;
  const int bh = blockIdx.x, qt = blockIdx.y;
  const int q0 = qt * 128;
  const int tid = threadIdx.x, w = tid >> 6, lane = tid & 63;
  const int quad = lane >> 4, l16 = lane & 15;

  __shared__ __align__(16) _Float16 Kh[8192];   // 64 x 128, granule layout
  __shared__ __align__(16) _Float16 Vt[8192];   // 128 x 64, granule layout
  __shared__ __align__(16) _Float16 Pb[4][16 * 72];  // per-wave, padded

  const size_t qkbase = (size_t)bh * T * HD;

  half8 qh[2][4], ql[2][4];
#pragma unroll
  for (int i = 0; i < 2; i++)
#pragma unroll
    for (int s = 0; s < 4; s++) {
      size_t off = qkbase + (size_t)(q0 + w * 32 + i * 16 + l16) * HD + s * 32 + quad * 8;
      qh[i][s] = *(const half8*)(qhp + off);
      ql[i][s] = *(const half8*)(qlp + off);
    }

  floatx4 o[2][8];
#pragma unroll
  for (int i = 0; i < 2; i++)
#pragma unroll
    for (int dt = 0; dt < 8; dt++) o[i][dt] = (floatx4){0.f, 0.f, 0.f, 0.f};
  float mrow[2][4], lrow[2][4];
#pragma unroll
  for (int i = 0; i < 2; i++)
#pragma unroll
    for (int r = 0; r < 4; r++) { mrow[i][r] = -3e38f; lrow[i][r] = 0.f; }

  const int ntiles = q0 / 64 + 2;
  for (int kt = 0; kt < ntiles; ++kt) {
    const int s0 = kt * 64;
    __syncthreads();
    for (int c = w; c < 16; c += 4) {
      int tt = c >> 2, ss = c & 3;
      size_t go = qkbase + (size_t)(s0 + tt * 16 + l16) * HD + ss * 32 + quad * 8;
      async16(&Kh[c * 512], khp + go);
      int dt = c >> 1, vs = c & 1;
      size_t vo = (size_t)bh * HD * T + (size_t)(dt * 16 + l16) * T + s0 + vs * 32 + quad * 8;
      async16(&Vt[c * 512], vtp + vo);
    }
    __syncthreads();

    floatx4 S[2][4];
#pragma unroll
    for (int i = 0; i < 2; i++)
#pragma unroll
      for (int j = 0; j < 4; j++) S[i][j] = (floatx4){0.f, 0.f, 0.f, 0.f};

#pragma unroll
    for (int s = 0; s < 4; s++) {
#pragma unroll
      for (int j = 0; j < 4; j++) {
        half8 kh = ld8h(&Kh[(j * 4 + s) * 512 + lane * 8]);
        S[0][j] = MFMA16H(qh[0][s], kh, S[0][j]);
        S[1][j] = MFMA16H(qh[1][s], kh, S[1][j]);
        S[0][j] = MFMA16H(ql[0][s], kh, S[0][j]);
        S[1][j] = MFMA16H(ql[1][s], kh, S[1][j]);
      }
    }

    if (s0 + 63 > q0) {  // causal mask (near-diagonal tiles only)
#pragma unroll
      for (int i = 0; i < 2; i++) {
        int rb = q0 + w * 32 + i * 16 + quad * 4;
#pragma unroll
        for (int j = 0; j < 4; j++) {
          int cg = s0 + j * 16 + l16;
#pragma unroll
          for (int r = 0; r < 4; r++)
            if (cg > rb + r) S[i][j][r] = -3e38f;
        }
      }
    }

    half8 pf[2][2];
#pragma unroll
    for (int i = 0; i < 2; i++) {
#pragma unroll
      for (int r = 0; r < 4; r++) {
        float mx = fmaxf(fmaxf(S[i][0][r], S[i][1][r]), fmaxf(S[i][2][r], S[i][3][r]));
#pragma unroll
        for (int d = 1; d < 16; d <<= 1) mx = fmaxf(mx, __shfl_xor(mx, d, 64));
        float mnew = fmaxf(mrow[i][r], mx);
        float al = __expf(mrow[i][r] - mnew);
        mrow[i][r] = mnew;
        float sum = 0.f;
#pragma unroll
        for (int j = 0; j < 4; j++) {
          float p = __expf(S[i][j][r] - mnew);
          S[i][j][r] = p;
          sum += p;
        }
#pragma unroll
        for (int d = 1; d < 16; d <<= 1) sum += __shfl_xor(sum, d, 64);
        lrow[i][r] = lrow[i][r] * al + sum;
#pragma unroll
        for (int dt = 0; dt < 8; dt++) o[i][dt][r] *= al;
      }
      // P -> LDS (A-fragment transform); per-wave buffer, DS in-order per wave
#pragma unroll
      for (int r = 0; r < 4; r++)
#pragma unroll
        for (int j = 0; j < 4; j++)
          Pb[w][(quad * 4 + r) * 72 + j * 16 + l16] = (_Float16)S[i][j][r];
      pf[i][0] = ld8h(&Pb[w][l16 * 72 + quad * 8]);
      pf[i][1] = ld8h(&Pb[w][l16 * 72 + 32 + quad * 8]);
    }

#pragma unroll
    for (int dt = 0; dt < 8; dt++) {
#pragma unroll
      for (int s = 0; s < 2; s++) {
        half8 vf = ld8h(&Vt[(dt * 2 + s) * 512 + lane * 8]);
        o[0][dt] = MFMA16H(pf[0][s], vf, o[0][dt]);
        o[1][dt] = MFMA16H(pf[1][s], vf, o[1][dt]);
      }
    }
  }

  const int b = bh >> 4, h = bh & 15;
#pragma unroll
  for (int i = 0; i < 2; i++) {
#pragma unroll
    for (int r = 0; r < 4; r++) {
      int trow = q0 + w * 32 + i * 16 + quad * 4 + r;
      float linv = 1.0f / lrow[i][r];
      size_t base = ((size_t)(b * T + trow)) * 2048 + h * 128;
#pragma unroll
      for (int dt = 0; dt < 8; dt++)
        aout[base + dt * 16 + l16] = (_Float16)(o[i][dt][r] * linv);
    }
  }
}

// ---------------------------------------------------------------------------
// O projection: y = aout @ Wo^T, fp16 in, fp32 out. 128x128 tile, BK=64.
// ---------------------------------------------------------------------------
__global__ __launch_bounds__(256, 2) void gemm_o_f16(
    const _Float16* __restrict__ A, const _Float16* __restrict__ B,
    float* __restrict__ outF) {
  constexpr int Kd = 2048;
  constexpr int Nd = 2048;
  const int n0 = blockIdx.x * 128, m0 = blockIdx.y * 128;
  const int tid = threadIdx.x, w = tid >> 6, lane = tid & 63;
  const int quad = lane >> 4, l16 = lane & 15;

  __shared__ __align__(16) _Float16 As[8192];  // two 32-k sub-tiles
  __shared__ __align__(16) _Float16 Bs[8192];

  floatx4 acc[2][8];
#pragma unroll
  for (int i = 0; i < 2; i++)
#pragma unroll
    for (int j = 0; j < 8; j++) acc[i][j] = (floatx4){0.f, 0.f, 0.f, 0.f};

  const int t0 = 2 * w, t1 = 2 * w + 1;
  const size_t ao0 = (size_t)(m0 + t0 * 16 + l16) * Kd + quad * 8;
  const size_t ao1 = (size_t)(m0 + t1 * 16 + l16) * Kd + quad * 8;
  const size_t bo0 = (size_t)(n0 + t0 * 16 + l16) * Kd + quad * 8;
  const size_t bo1 = (size_t)(n0 + t1 * 16 + l16) * Kd + quad * 8;

  for (int k0 = 0; k0 < Kd; k0 += 64) {
    __syncthreads();
    async16(&As[t0 * 512], A + ao0 + k0);
    async16(&As[t1 * 512], A + ao1 + k0);
    async16(&As[4096 + t0 * 512], A + ao0 + k0 + 32);
    async16(&As[4096 + t1 * 512], A + ao1 + k0 + 32);
    async16(&Bs[t0 * 512], B + bo0 + k0);
    async16(&Bs[t1 * 512], B + bo1 + k0);
    async16(&Bs[4096 + t0 * 512], B + bo0 + k0 + 32);
    async16(&Bs[4096 + t1 * 512], B + bo1 + k0 + 32);
    __syncthreads();
    half8 a00 = ld8h(&As[t0 * 512 + lane * 8]);
    half8 a10 = ld8h(&As[t1 * 512 + lane * 8]);
    half8 a01 = ld8h(&As[4096 + t0 * 512 + lane * 8]);
    half8 a11 = ld8h(&As[4096 + t1 * 512 + lane * 8]);
#pragma unroll
    for (int j = 0; j < 8; j++) {
      half8 b0 = ld8h(&Bs[j * 512 + lane * 8]);
      acc[0][j] = MFMA16H(a00, b0, acc[0][j]);
      acc[1][j] = MFMA16H(a10, b0, acc[1][j]);
      half8 b1 = ld8h(&Bs[4096 + j * 512 + lane * 8]);
      acc[0][j] = MFMA16H(a01, b1, acc[0][j]);
      acc[1][j] = MFMA16H(a11, b1, acc[1][j]);
    }
  }

#pragma unroll
  for (int i = 0; i < 2; i++) {
    int rbase = m0 + (2 * w + i) * 16 + quad * 4;
#pragma unroll
    for (int j = 0; j < 8; j++) {
      int col = n0 + j * 16 + l16;
#pragma unroll
      for (int r = 0; r < 4; r++)
        outF[(size_t)(rbase + r) * Nd + col] = acc[i][j][r];
    }
  }
}

// ---------------------------------------------------------------------------
// per-row L2 normalize: out = y / max(||y||, 1e-12)
// ---------------------------------------------------------------------------
__global__ __launch_bounds__(256) void rownorm(const float* __restrict__ y,
                                               float* __restrict__ out) {
  int row = blockIdx.x;
  const float4* yr = (const float4*)(y + (size_t)row * 2048);
  float4* od = (float4*)(out + (size_t)row * 2048);
  int t = threadIdx.x;
  float4 v0 = yr[t], v1 = yr[t + 256];
  float ss = v0.x * v0.x + v0.y * v0.y + v0.z * v0.z + v0.w * v0.w +
             v1.x * v1.x + v1.y * v1.y + v1.z * v1.z + v1.w * v1.w;
#pragma unroll
  for (int d = 1; d < 64; d <<= 1) ss += __shfl_xor(ss, d, 64);
  __shared__ float red[4];
  if ((t & 63) == 0) red[t >> 6] = ss;
  __syncthreads();
  float tot = red[0] + red[1] + red[2] + red[3];
  float inv = 1.0f / fmaxf(sqrtf(tot), 1e-12f);
  v0.x *= inv; v0.y *= inv; v0.z *= inv; v0.w *= inv;
  v1.x *= inv; v1.y *= inv; v1.z *= inv; v1.w *= inv;
  od[t] = v0;
  od[t + 256] = v1;
}

// ---------------------------------------------------------------------------
extern "C" void kernel_launch(void* const* d_in, const int* in_sizes, int n_in,
                              void* d_out, int out_size, void* d_ws, size_t ws_size,
                              hipStream_t stream) {
  (void)in_sizes; (void)n_in; (void)out_size; (void)ws_size;
  const float* x   = (const float*)d_in[0];
  const float* Wq  = (const float*)d_in[1];
  const float* Wk  = (const float*)d_in[2];
  const float* Wv  = (const float*)d_in[3];
  const float* Wo  = (const float*)d_in[4];
  const float* sqk = (const float*)d_in[5];
  char* ws = (char*)d_ws;

  constexpr size_t SZX = 8388608ull * 2;  // fp16 x-sized buffer (16 MB)
  constexpr size_t SZW = 4194304ull * 2;  // fp16 weight buffer (8 MB)

  size_t o_xh = 0;
  size_t o_xl = o_xh + SZX;
  size_t o_wq = o_xl + SZX;
  size_t o_wk = o_wq + SZW;
  size_t o_wv = o_wk + SZW;
  size_t o_wo = o_wv + SZW;
  size_t o_qh = o_wo + SZW;
  size_t o_ql = o_qh + SZX;
  size_t o_kh = o_ql + SZX;
  size_t o_v  = o_kh + SZX;
  size_t o_vt = o_v + SZX;
  size_t o_cos = o_vt + SZX;
  size_t o_sin = o_cos + 2048 * 64 * 4;
  // aliases (lifetimes disjoint):
  size_t o_aout = o_wq;  // 16 MB over wq+wk (dead after QKV proj)
  size_t o_y    = o_qh;  // 32 MB fp32 over qh+ql (dead after flash)

  _Float16* xh = (_Float16*)(ws + o_xh);
  _Float16* xl = (_Float16*)(ws + o_xl);
  _Float16* wq = (_Float16*)(ws + o_wq);
  _Float16* wk = (_Float16*)(ws + o_wk);
  _Float16* wv = (_Float16*)(ws + o_wv);
  _Float16* wo = (_Float16*)(ws + o_wo);
  _Float16* qh = (_Float16*)(ws + o_qh);
  _Float16* ql = (_Float16*)(ws + o_ql);
  _Float16* kh = (_Float16*)(ws + o_kh);
  _Float16* v  = (_Float16*)(ws + o_v);
  _Float16* vt = (_Float16*)(ws + o_vt);
  float* cosT = (float*)(ws + o_cos);
  float* sinT = (float*)(ws + o_sin);
  _Float16* aout = (_Float16*)(ws + o_aout);
  float* y = (float*)(ws + o_y);

  cvt_prep<<<8192, 256, 0, stream>>>((const float4*)x, (const float4*)Wq,
                                     (const float4*)Wk, (const float4*)Wv,
                                     (const float4*)Wo, (half4v*)xh, (half4v*)xl,
                                     (half4v*)wq, (half4v*)wk, (half4v*)wv,
                                     (half4v*)wo, cosT, sinT);

  gemm_qkv_f16<<<dim3(16, 32), 512, 0, stream>>>(xh, xl, wq, wk, wv, cosT,
                                                 sinT, sqk, qh, ql, kh, v);
  transpose_v<<<dim3(64, 4, 32), 256, 0, stream>>>((const unsigned short*)v,
                                                   (unsigned short*)vt);

  flash_attn<<<dim3(32, 16), 256, 0, stream>>>(qh, ql, kh, vt, aout);

  gemm_o_f16<<<dim3(16, 32), 256, 0, stream>>>(aout, wo, y);
  rownorm<<<4096, 256, 0, stream>>>(y, (float*)d_out);
}

// Round 2
// 534.318 us; speedup vs baseline: 1.0028x; 1.0028x over previous
//
#include <hip/hip_runtime.h>

#define DEVFN __device__ __forceinline__

typedef float    floatx4 __attribute__((ext_vector_type(4)));
typedef _Float16 half8   __attribute__((ext_vector_type(8)));
typedef _Float16 half4v  __attribute__((ext_vector_type(4)));

#define MFMA16H(a, b, c) __builtin_amdgcn_mfma_f32_16x16x32_f16((a), (b), (c), 0, 0, 0)

DEVFN void async16(void* lds, const void* g) {
  __builtin_amdgcn_global_load_lds(
      (const __attribute__((address_space(1))) unsigned int*)g,
      (__attribute__((address_space(3))) unsigned int*)lds, 16, 0, 0);
}
DEVFN half8 ld8h(const _Float16* p) { return *(const half8*)p; }

// ---------------------------------------------------------------------------
// prep: x -> fp16 hi/lo split; Wq,Wk,Wv,Wo -> fp16; rope tables (fp64) folded
// ---------------------------------------------------------------------------
__global__ __launch_bounds__(256) void cvt_prep(
    const float4* __restrict__ x, const float4* __restrict__ wq,
    const float4* __restrict__ wk, const float4* __restrict__ wv,
    const float4* __restrict__ wo,
    half4v* __restrict__ xh, half4v* __restrict__ xl,
    half4v* __restrict__ qo, half4v* __restrict__ ko,
    half4v* __restrict__ vo, half4v* __restrict__ oo,
    float* __restrict__ cosT, float* __restrict__ sinT) {
  int i = blockIdx.x * 256 + threadIdx.x;  // grid covers 2097152 float4 of x
  {
    float4 v = x[i];
    half4v h = {(_Float16)v.x, (_Float16)v.y, (_Float16)v.z, (_Float16)v.w};
    half4v l = {(_Float16)(v.x - (float)h.x), (_Float16)(v.y - (float)h.y),
                (_Float16)(v.z - (float)h.z), (_Float16)(v.w - (float)h.w)};
    xh[i] = h;
    xl[i] = l;
  }
  if (i < 1048576) {
    float4 v = wq[i];
    qo[i] = (half4v){(_Float16)v.x, (_Float16)v.y, (_Float16)v.z, (_Float16)v.w};
    v = wk[i];
    ko[i] = (half4v){(_Float16)v.x, (_Float16)v.y, (_Float16)v.z, (_Float16)v.w};
    v = wv[i];
    vo[i] = (half4v){(_Float16)v.x, (_Float16)v.y, (_Float16)v.z, (_Float16)v.w};
    v = wo[i];
    oo[i] = (half4v){(_Float16)v.x, (_Float16)v.y, (_Float16)v.z, (_Float16)v.w};
  }
  if (i < 131072) {  // rope tables: t = i>>6, d = i&63
    int t = i >> 6, d = i & 63;
    double theta = exp(-((double)(2 * d) / 128.0) * log(10000.0));
    double ang = (double)t * theta;
    cosT[i] = (float)cos(ang);
    sinT[i] = (float)sin(ang);
  }
}

// ---------------------------------------------------------------------------
// Q+K projection, fp16 2-pass (x split exact, W fp16-rounded). 256x128 tile,
// BK=32, 512 threads / 8 waves. Wave owns 64 rows x 64 cols per matrix
// (4x4 fragment grid), cols = granules {2c0,2c0+1,2c0+4,2c0+5} so RoPE pairs
// (d, d+64) are wave-local. 2 phases/K-step, 32-MFMA clusters, X 2-buffered,
// W 3-buffered (112 KB LDS, 1 block/CU), counted vmcnt(2) boundary waits.
// Epilogue: RoPE fp32; Q split-fp16 (hi+lo), K single fp16, at [B,NH,T,HD].
// ---------------------------------------------------------------------------
__global__ __launch_bounds__(512, 2) void gemm_qk_f16(
    const _Float16* __restrict__ xhp, const _Float16* __restrict__ xlp,
    const _Float16* __restrict__ wqp, const _Float16* __restrict__ wkp,
    const float* __restrict__ cosT, const float* __restrict__ sinT,
    const float* __restrict__ sqk,
    _Float16* __restrict__ qhi, _Float16* __restrict__ qlo,
    _Float16* __restrict__ khi) {
  constexpr int Kd = 2048, NT = 64;
  const int n0 = blockIdx.x * 128, m0 = blockIdx.y * 256;
  const int tid = threadIdx.x, w = tid >> 6, lane = tid & 63;
  const int quad = lane >> 4, l16 = lane & 15;
  const int c0 = w & 1, rb = w >> 1, rgb = rb * 4;
  const int cgr0 = 2 * c0, cgr1 = 2 * c0 + 1, cgr2 = 2 * c0 + 4, cgr3 = 2 * c0 + 5;

  // LDS (halves): XH[2][8192] XL[2][8192] WQ[3][4096] WK[3][4096] = 112 KB
  __shared__ __align__(16) _Float16 smem[57344];
  _Float16* XH = smem;
  _Float16* XL = smem + 16384;
  _Float16* WQ = smem + 32768;
  _Float16* WK = smem + 45056;

  floatx4 accQ[4][4], accK[4][4];
#pragma unroll
  for (int i = 0; i < 4; i++)
#pragma unroll
    for (int c = 0; c < 4; c++) {
      accQ[i][c] = (floatx4){0.f, 0.f, 0.f, 0.f};
      accK[i][c] = (floatx4){0.f, 0.f, 0.f, 0.f};
    }

  // wave w stages X granules {2w, 2w+1}, W granule w (fragment-linear layout)
  const size_t xg0 = (size_t)(m0 + 32 * w + l16) * Kd + quad * 8;
  const size_t xg1 = xg0 + (size_t)16 * Kd;
  const size_t wg = (size_t)(n0 + 16 * w + l16) * Kd + quad * 8;

#define STAGE_X(T)                                                      \
  {                                                                     \
    const int kk_ = (T) * 32;                                           \
    _Float16* bx_ = XH + ((T) & 1) * 8192;                              \
    _Float16* bl_ = XL + ((T) & 1) * 8192;                              \
    async16(bx_ + (2 * w) * 512, xhp + xg0 + kk_);                      \
    async16(bx_ + (2 * w + 1) * 512, xhp + xg1 + kk_);                  \
    async16(bl_ + (2 * w) * 512, xlp + xg0 + kk_);                      \
    async16(bl_ + (2 * w + 1) * 512, xlp + xg1 + kk_);                  \
  }
#define STAGE_W(T)                                                      \
  {                                                                     \
    const int kk_ = (T) * 32;                                           \
    async16(WQ + ((T) % 3) * 4096 + w * 512, wqp + wg + kk_);           \
    async16(WK + ((T) % 3) * 4096 + w * 512, wkp + wg + kk_);           \
  }

  // prologue: X(0), W(0), W(1) -> wait X0,W0 (newest 2 = W(1) stay in flight)
  STAGE_X(0);
  STAGE_W(0);
  STAGE_W(1);
  asm volatile("s_waitcnt vmcnt(2)" ::: "memory");
  __builtin_amdgcn_s_barrier();

#pragma unroll 1
  for (int t = 0; t < NT; ++t) {
    const _Float16* XH_ = XH + (t & 1) * 8192;
    const _Float16* XL_ = XL + (t & 1) * 8192;
    const _Float16* WQ_ = WQ + (t % 3) * 4096;
    const _Float16* WK_ = WK + (t % 3) * 4096;

    // ---- phase 0: A-frags + Bq; stage X(t+1); 32 MFMA (Q hi+lo) ----
    half8 ah[4], al[4], bq[4];
#pragma unroll
    for (int i = 0; i < 4; i++) {
      ah[i] = ld8h(XH_ + (rgb + i) * 512 + lane * 8);
      al[i] = ld8h(XL_ + (rgb + i) * 512 + lane * 8);
    }
    bq[0] = ld8h(WQ_ + cgr0 * 512 + lane * 8);
    bq[1] = ld8h(WQ_ + cgr1 * 512 + lane * 8);
    bq[2] = ld8h(WQ_ + cgr2 * 512 + lane * 8);
    bq[3] = ld8h(WQ_ + cgr3 * 512 + lane * 8);
    if (t + 1 < NT) STAGE_X(t + 1);
    __builtin_amdgcn_s_barrier();
    asm volatile("s_waitcnt lgkmcnt(0)");
    __builtin_amdgcn_sched_barrier(0);
    __builtin_amdgcn_s_setprio(1);
#pragma unroll
    for (int i = 0; i < 4; i++)
#pragma unroll
      for (int c = 0; c < 4; c++)
        accQ[i][c] = MFMA16H(ah[i], bq[c], accQ[i][c]);
#pragma unroll
    for (int i = 0; i < 4; i++)
#pragma unroll
      for (int c = 0; c < 4; c++)
        accQ[i][c] = MFMA16H(al[i], bq[c], accQ[i][c]);
    __builtin_amdgcn_s_setprio(0);
    __builtin_amdgcn_s_barrier();

    // ---- phase 1: Bk; stage W(t+2); 32 MFMA (K hi+lo) ----
    half8 bk[4];
    bk[0] = ld8h(WK_ + cgr0 * 512 + lane * 8);
    bk[1] = ld8h(WK_ + cgr1 * 512 + lane * 8);
    bk[2] = ld8h(WK_ + cgr2 * 512 + lane * 8);
    bk[3] = ld8h(WK_ + cgr3 * 512 + lane * 8);
    if (t + 2 < NT) STAGE_W(t + 2);
    __builtin_amdgcn_s_barrier();
    asm volatile("s_waitcnt lgkmcnt(0)");
    __builtin_amdgcn_sched_barrier(0);
    __builtin_amdgcn_s_setprio(1);
#pragma unroll
    for (int i = 0; i < 4; i++)
#pragma unroll
      for (int c = 0; c < 4; c++)
        accK[i][c] = MFMA16H(ah[i], bk[c], accK[i][c]);
#pragma unroll
    for (int i = 0; i < 4; i++)
#pragma unroll
      for (int c = 0; c < 4; c++)
        accK[i][c] = MFMA16H(al[i], bk[c], accK[i][c]);
    __builtin_amdgcn_s_setprio(0);

    // boundary: newest 2 outstanding = W(t+2); X(t+1), W(t+1) guaranteed done
    if (t + 2 < NT) {
      asm volatile("s_waitcnt vmcnt(2)" ::: "memory");
    } else {
      asm volatile("s_waitcnt vmcnt(0)" ::: "memory");
    }
    __builtin_amdgcn_s_barrier();
  }
#undef STAGE_X
#undef STAGE_W

  // ---- epilogue: RoPE + store, staged through dead K-loop LDS ----
  _Float16* stH = smem + w * 1152;          // 16 x 72 halves per wave
  _Float16* stL = smem + 9216 + w * 1152;

  const int h = n0 >> 7;
  const int b = m0 >> 11;

#pragma unroll
  for (int rg = 0; rg < 4; rg++) {
    const int tt0 = (m0 & 2047) + rb * 64 + rg * 16;
    const size_t gbase = (((size_t)(b * 16 + h)) * 2048 + tt0) * 128;

    // ---- Q: RoPE + sqk*sqrt(2048)*sqrt(128), split-fp16 ----
#pragma unroll
    for (int cj = 0; cj < 2; cj++) {
      int d = c0 * 32 + cj * 16 + l16;
      float s1 = sqk[h * 128 + d] * 512.0f;
      float s2 = sqk[h * 128 + d + 64] * 512.0f;
#pragma unroll
      for (int r = 0; r < 4; r++) {
        int tq = tt0 + quad * 4 + r;
        float cc = cosT[tq * 64 + d], sn = sinT[tq * 64 + d];
        float xr = accQ[rg][cj][r], xi = accQ[rg][cj + 2][r];
        float o1 = (xr * cc - xi * sn) * s1;
        float o2 = (xr * sn + xi * cc) * s2;
        _Float16 h1 = (_Float16)o1, h2 = (_Float16)o2;
        int rl = quad * 4 + r;
        stH[rl * 72 + cj * 16 + l16] = h1;
        stH[rl * 72 + 32 + cj * 16 + l16] = h2;
        stL[rl * 72 + cj * 16 + l16] = (_Float16)(o1 - (float)h1);
        stL[rl * 72 + 32 + cj * 16 + l16] = (_Float16)(o2 - (float)h2);
      }
    }
#pragma unroll
    for (int it = 0; it < 2; it++) {
      int row = it * 8 + (lane >> 3), pc = (lane & 7) * 8;
      int d = (pc < 32) ? (c0 * 32 + pc) : (64 + c0 * 32 + (pc - 32));
      size_t ga = gbase + (size_t)row * 128 + d;
      *(half8*)(qhi + ga) = ld8h(&stH[row * 72 + pc]);
      *(half8*)(qlo + ga) = ld8h(&stL[row * 72 + pc]);
    }

    // ---- K: RoPE + sqk*sqrt(2048), single fp16 ----
#pragma unroll
    for (int cj = 0; cj < 2; cj++) {
      int d = c0 * 32 + cj * 16 + l16;
      float s1 = sqk[h * 128 + d] * 45.254834f;
      float s2 = sqk[h * 128 + d + 64] * 45.254834f;
#pragma unroll
      for (int r = 0; r < 4; r++) {
        int tq = tt0 + quad * 4 + r;
        float cc = cosT[tq * 64 + d], sn = sinT[tq * 64 + d];
        float xr = accK[rg][cj][r], xi = accK[rg][cj + 2][r];
        int rl = quad * 4 + r;
        stH[rl * 72 + cj * 16 + l16] = (_Float16)((xr * cc - xi * sn) * s1);
        stH[rl * 72 + 32 + cj * 16 + l16] = (_Float16)((xr * sn + xi * cc) * s2);
      }
    }
#pragma unroll
    for (int it = 0; it < 2; it++) {
      int row = it * 8 + (lane >> 3), pc = (lane & 7) * 8;
      int d = (pc < 32) ? (c0 * 32 + pc) : (64 + c0 * 32 + (pc - 32));
      *(half8*)(khi + gbase + (size_t)row * 128 + d) = ld8h(&stH[row * 72 + pc]);
    }
  }
}

// ---------------------------------------------------------------------------
// V projection, fp16 1-pass (x hi only). Same 256x128 tiling, single phase
// per K-step (16-MFMA cluster), X 2-buffered + Wv 3-buffered (56 KB LDS,
// 2 blocks/CU), counted vmcnt(1). Epilogue writes vt = V^T directly
// ([BH][HD][T]) via LDS transpose staging -> transpose_v kernel eliminated.
// ---------------------------------------------------------------------------
__global__ __launch_bounds__(512, 2) void gemm_v_f16(
    const _Float16* __restrict__ xhp, const _Float16* __restrict__ wvp,
    _Float16* __restrict__ vt) {
  constexpr int Kd = 2048, NT = 64;
  const int n0 = blockIdx.x * 128, m0 = blockIdx.y * 256;
  const int tid = threadIdx.x, w = tid >> 6, lane = tid & 63;
  const int quad = lane >> 4, l16 = lane & 15;
  const int c0 = w & 1, rb = w >> 1, rgb = rb * 4;

  // LDS (halves): XH[2][8192] WV[3][4096] = 56 KB
  __shared__ __align__(16) _Float16 smem[28672];
  _Float16* XH = smem;
  _Float16* WV = smem + 16384;

  floatx4 accV[4][4];
#pragma unroll
  for (int i = 0; i < 4; i++)
#pragma unroll
    for (int c = 0; c < 4; c++) accV[i][c] = (floatx4){0.f, 0.f, 0.f, 0.f};

  const size_t xg0 = (size_t)(m0 + 32 * w + l16) * Kd + quad * 8;
  const size_t xg1 = xg0 + (size_t)16 * Kd;
  const size_t wg = (size_t)(n0 + 16 * w + l16) * Kd + quad * 8;

#define STAGE_XV(T)                                                     \
  {                                                                     \
    const int kk_ = (T) * 32;                                           \
    _Float16* bx_ = XH + ((T) & 1) * 8192;                              \
    async16(bx_ + (2 * w) * 512, xhp + xg0 + kk_);                      \
    async16(bx_ + (2 * w + 1) * 512, xhp + xg1 + kk_);                  \
  }
#define STAGE_WV(T)                                                     \
  { async16(WV + ((T) % 3) * 4096 + w * 512, wvp + wg + (T) * 32); }

  STAGE_XV(0);
  STAGE_WV(0);
  STAGE_WV(1);
  asm volatile("s_waitcnt vmcnt(1)" ::: "memory");
  __builtin_amdgcn_s_barrier();

#pragma unroll 1
  for (int t = 0; t < NT; ++t) {
    const _Float16* XH_ = XH + (t & 1) * 8192;
    const _Float16* WV_ = WV + (t % 3) * 4096;

    half8 ah[4], bv[4];
#pragma unroll
    for (int i = 0; i < 4; i++)
      ah[i] = ld8h(XH_ + (rgb + i) * 512 + lane * 8);
#pragma unroll
    for (int c = 0; c < 4; c++)
      bv[c] = ld8h(WV_ + (4 * c0 + c) * 512 + lane * 8);
    if (t + 1 < NT) STAGE_XV(t + 1);
    if (t + 2 < NT) STAGE_WV(t + 2);
    __builtin_amdgcn_s_barrier();
    asm volatile("s_waitcnt lgkmcnt(0)");
    __builtin_amdgcn_sched_barrier(0);
    __builtin_amdgcn_s_setprio(1);
#pragma unroll
    for (int i = 0; i < 4; i++)
#pragma unroll
      for (int c = 0; c < 4; c++)
        accV[i][c] = MFMA16H(ah[i], bv[c], accV[i][c]);
    __builtin_amdgcn_s_setprio(0);
    if (t + 2 < NT) {
      asm volatile("s_waitcnt vmcnt(1)" ::: "memory");
    } else {
      asm volatile("s_waitcnt vmcnt(0)" ::: "memory");
    }
    __builtin_amdgcn_s_barrier();
  }
#undef STAGE_XV
#undef STAGE_WV

  // ---- epilogue: write vt[bh][d][t] via per-wave LDS transpose staging ----
  _Float16* stV = smem + w * 1024;  // [64 d][16 t] halves per wave

  const int h = n0 >> 7;
  const int b = m0 >> 11;
  const int bh = b * 16 + h;

#pragma unroll
  for (int rg = 0; rg < 4; rg++) {
    const int tt0 = (m0 & 2047) + rb * 64 + rg * 16;
#pragma unroll
    for (int c = 0; c < 4; c++)
#pragma unroll
      for (int r = 0; r < 4; r++)
        stV[(c * 16 + l16) * 16 + quad * 4 + r] = (_Float16)accV[rg][c][r];
#pragma unroll
    for (int it = 0; it < 2; it++) {
      int dl = it * 32 + (lane >> 1), th = (lane & 1) * 8;
      int dh = c0 * 64 + dl;
      size_t ga = ((size_t)bh * 128 + dh) * 2048 + tt0 + th;
      *(half8*)(vt + ga) = ld8h(&stV[dl * 16 + th]);
    }
  }
}

// ---------------------------------------------------------------------------
// flash attention: block = (bh, 128 q-rows). 4 waves x 32 rows, K-tiles of
// 64, K/V LDS double-buffered: stage kt+1 at iter top (8 global_load_lds),
// compute kt, sync at bottom (drain covered by ~3k cycles of compute).
// QK^T 2-pass (q split exact, k fp16-rounded), online softmax fp32, PV fp16.
// ---------------------------------------------------------------------------
__global__ __launch_bounds__(256, 2) void flash_attn(
    const _Float16* __restrict__ qhp, const _Float16* __restrict__ qlp,
    const _Float16* __restrict__ khp,
    const _Float16* __restrict__ vtp, _Float16* __restrict__ aout) {
  constexpr int T = 2048, HD = 128;
  const int bh = blockIdx.x, qt = blockIdx.y;
  const int q0 = qt * 128;
  const int tid = threadIdx.x, w = tid >> 6, lane = tid & 63;
  const int quad = lane >> 4, l16 = lane & 15;

  __shared__ __align__(16) _Float16 Kh[2][8192];   // 64 x 128, granule layout
  __shared__ __align__(16) _Float16 Vt[2][8192];   // 128 x 64, granule layout
  __shared__ __align__(16) _Float16 Pb[4][16 * 72];  // per-wave, padded

  const size_t qkbase = (size_t)bh * T * HD;

  half8 qh[2][4], ql[2][4];
#pragma unroll
  for (int i = 0; i < 2; i++)
#pragma unroll
    for (int s = 0; s < 4; s++) {
      size_t off = qkbase + (size_t)(q0 + w * 32 + i * 16 + l16) * HD + s * 32 + quad * 8;
      qh[i][s] = *(const half8*)(qhp + off);
      ql[i][s] = *(const half8*)(qlp + off);
    }

  floatx4 o[2][8];
#pragma unroll
  for (int i = 0; i < 2; i++)
#pragma unroll
    for (int dt = 0; dt < 8; dt++) o[i][dt] = (floatx4){0.f, 0.f, 0.f, 0.f};
  float mrow[2][4], lrow[2][4];
#pragma unroll
  for (int i = 0; i < 2; i++)
#pragma unroll
    for (int r = 0; r < 4; r++) { mrow[i][r] = -3e38f; lrow[i][r] = 0.f; }

  const int ntiles = q0 / 64 + 2;

  auto stageKV = [&](int kt, int set) {
    const int s0 = kt * 64;
    for (int c = w; c < 16; c += 4) {
      int tt = c >> 2, ss = c & 3;
      size_t go = qkbase + (size_t)(s0 + tt * 16 + l16) * HD + ss * 32 + quad * 8;
      async16(&Kh[set][c * 512], khp + go);
      int dt = c >> 1, vs = c & 1;
      size_t vo = (size_t)bh * HD * T + (size_t)(dt * 16 + l16) * T + s0 + vs * 32 + quad * 8;
      async16(&Vt[set][c * 512], vtp + vo);
    }
  };

  stageKV(0, 0);
  __syncthreads();

  for (int kt = 0; kt < ntiles; ++kt) {
    const int s0 = kt * 64;
    const int set = kt & 1;
    if (kt + 1 < ntiles) stageKV(kt + 1, set ^ 1);

    floatx4 S[2][4];
#pragma unroll
    for (int i = 0; i < 2; i++)
#pragma unroll
      for (int j = 0; j < 4; j++) S[i][j] = (floatx4){0.f, 0.f, 0.f, 0.f};

#pragma unroll
    for (int s = 0; s < 4; s++) {
#pragma unroll
      for (int j = 0; j < 4; j++) {
        half8 kh = ld8h(&Kh[set][(j * 4 + s) * 512 + lane * 8]);
        S[0][j] = MFMA16H(qh[0][s], kh, S[0][j]);
        S[1][j] = MFMA16H(qh[1][s], kh, S[1][j]);
        S[0][j] = MFMA16H(ql[0][s], kh, S[0][j]);
        S[1][j] = MFMA16H(ql[1][s], kh, S[1][j]);
      }
    }

    if (s0 + 63 > q0) {  // causal mask (near-diagonal tiles only)
#pragma unroll
      for (int i = 0; i < 2; i++) {
        int rb = q0 + w * 32 + i * 16 + quad * 4;
#pragma unroll
        for (int j = 0; j < 4; j++) {
          int cg = s0 + j * 16 + l16;
#pragma unroll
          for (int r = 0; r < 4; r++)
            if (cg > rb + r) S[i][j][r] = -3e38f;
        }
      }
    }

    half8 pf[2][2];
#pragma unroll
    for (int i = 0; i < 2; i++) {
#pragma unroll
      for (int r = 0; r < 4; r++) {
        float mx = fmaxf(fmaxf(S[i][0][r], S[i][1][r]), fmaxf(S[i][2][r], S[i][3][r]));
#pragma unroll
        for (int d = 1; d < 16; d <<= 1) mx = fmaxf(mx, __shfl_xor(mx, d, 64));
        float mnew = fmaxf(mrow[i][r], mx);
        float al = __expf(mrow[i][r] - mnew);
        mrow[i][r] = mnew;
        float sum = 0.f;
#pragma unroll
        for (int j = 0; j < 4; j++) {
          float p = __expf(S[i][j][r] - mnew);
          S[i][j][r] = p;
          sum += p;
        }
#pragma unroll
        for (int d = 1; d < 16; d <<= 1) sum += __shfl_xor(sum, d, 64);
        lrow[i][r] = lrow[i][r] * al + sum;
#pragma unroll
        for (int dt = 0; dt < 8; dt++) o[i][dt][r] *= al;
      }
      // P -> LDS (A-fragment transform); per-wave buffer, DS in-order per wave
#pragma unroll
      for (int r = 0; r < 4; r++)
#pragma unroll
        for (int j = 0; j < 4; j++)
          Pb[w][(quad * 4 + r) * 72 + j * 16 + l16] = (_Float16)S[i][j][r];
      pf[i][0] = ld8h(&Pb[w][l16 * 72 + quad * 8]);
      pf[i][1] = ld8h(&Pb[w][l16 * 72 + 32 + quad * 8]);
    }

#pragma unroll
    for (int dt = 0; dt < 8; dt++) {
#pragma unroll
      for (int s = 0; s < 2; s++) {
        half8 vf = ld8h(&Vt[set][(dt * 2 + s) * 512 + lane * 8]);
        o[0][dt] = MFMA16H(pf[0][s], vf, o[0][dt]);
        o[1][dt] = MFMA16H(pf[1][s], vf, o[1][dt]);
      }
    }
    __syncthreads();
  }

  const int b = bh >> 4, h = bh & 15;
#pragma unroll
  for (int i = 0; i < 2; i++) {
#pragma unroll
    for (int r = 0; r < 4; r++) {
      int trow = q0 + w * 32 + i * 16 + quad * 4 + r;
      float linv = 1.0f / lrow[i][r];
      size_t base = ((size_t)(b * T + trow)) * 2048 + h * 128;
#pragma unroll
      for (int dt = 0; dt < 8; dt++)
        aout[base + dt * 16 + l16] = (_Float16)(o[i][dt][r] * linv);
    }
  }
}

// ---------------------------------------------------------------------------
// O projection: y = aout @ Wo^T, fp16 in, fp32 out. 128x128 tile, BK=64.
// ---------------------------------------------------------------------------
__global__ __launch_bounds__(256, 2) void gemm_o_f16(
    const _Float16* __restrict__ A, const _Float16* __restrict__ B,
    float* __restrict__ outF) {
  constexpr int Kd = 2048;
  constexpr int Nd = 2048;
  const int n0 = blockIdx.x * 128, m0 = blockIdx.y * 128;
  const int tid = threadIdx.x, w = tid >> 6, lane = tid & 63;
  const int quad = lane >> 4, l16 = lane & 15;

  __shared__ __align__(16) _Float16 As[8192];  // two 32-k sub-tiles
  __shared__ __align__(16) _Float16 Bs[8192];

  floatx4 acc[2][8];
#pragma unroll
  for (int i = 0; i < 2; i++)
#pragma unroll
    for (int j = 0; j < 8; j++) acc[i][j] = (floatx4){0.f, 0.f, 0.f, 0.f};

  const int t0 = 2 * w, t1 = 2 * w + 1;
  const size_t ao0 = (size_t)(m0 + t0 * 16 + l16) * Kd + quad * 8;
  const size_t ao1 = (size_t)(m0 + t1 * 16 + l16) * Kd + quad * 8;
  const size_t bo0 = (size_t)(n0 + t0 * 16 + l16) * Kd + quad * 8;
  const size_t bo1 = (size_t)(n0 + t1 * 16 + l16) * Kd + quad * 8;

  for (int k0 = 0; k0 < Kd; k0 += 64) {
    __syncthreads();
    async16(&As[t0 * 512], A + ao0 + k0);
    async16(&As[t1 * 512], A + ao1 + k0);
    async16(&As[4096 + t0 * 512], A + ao0 + k0 + 32);
    async16(&As[4096 + t1 * 512], A + ao1 + k0 + 32);
    async16(&Bs[t0 * 512], B + bo0 + k0);
    async16(&Bs[t1 * 512], B + bo1 + k0);
    async16(&Bs[4096 + t0 * 512], B + bo0 + k0 + 32);
    async16(&Bs[4096 + t1 * 512], B + bo1 + k0 + 32);
    __syncthreads();
    half8 a00 = ld8h(&As[t0 * 512 + lane * 8]);
    half8 a10 = ld8h(&As[t1 * 512 + lane * 8]);
    half8 a01 = ld8h(&As[4096 + t0 * 512 + lane * 8]);
    half8 a11 = ld8h(&As[4096 + t1 * 512 + lane * 8]);
#pragma unroll
    for (int j = 0; j < 8; j++) {
      half8 b0 = ld8h(&Bs[j * 512 + lane * 8]);
      acc[0][j] = MFMA16H(a00, b0, acc[0][j]);
      acc[1][j] = MFMA16H(a10, b0, acc[1][j]);
      half8 b1 = ld8h(&Bs[4096 + j * 512 + lane * 8]);
      acc[0][j] = MFMA16H(a01, b1, acc[0][j]);
      acc[1][j] = MFMA16H(a11, b1, acc[1][j]);
    }
  }

#pragma unroll
  for (int i = 0; i < 2; i++) {
    int rbase = m0 + (2 * w + i) * 16 + quad * 4;
#pragma unroll
    for (int j = 0; j < 8; j++) {
      int col = n0 + j * 16 + l16;
#pragma unroll
      for (int r = 0; r < 4; r++)
        outF[(size_t)(rbase + r) * Nd + col] = acc[i][j][r];
    }
  }
}

// ---------------------------------------------------------------------------
// per-row L2 normalize: out = y / max(||y||, 1e-12)
// ---------------------------------------------------------------------------
__global__ __launch_bounds__(256) void rownorm(const float* __restrict__ y,
                                               float* __restrict__ out) {
  int row = blockIdx.x;
  const float4* yr = (const float4*)(y + (size_t)row * 2048);
  float4* od = (float4*)(out + (size_t)row * 2048);
  int t = threadIdx.x;
  float4 v0 = yr[t], v1 = yr[t + 256];
  float ss = v0.x * v0.x + v0.y * v0.y + v0.z * v0.z + v0.w * v0.w +
             v1.x * v1.x + v1.y * v1.y + v1.z * v1.z + v1.w * v1.w;
#pragma unroll
  for (int d = 1; d < 64; d <<= 1) ss += __shfl_xor(ss, d, 64);
  __shared__ float red[4];
  if ((t & 63) == 0) red[t >> 6] = ss;
  __syncthreads();
  float tot = red[0] + red[1] + red[2] + red[3];
  float inv = 1.0f / fmaxf(sqrtf(tot), 1e-12f);
  v0.x *= inv; v0.y *= inv; v0.z *= inv; v0.w *= inv;
  v1.x *= inv; v1.y *= inv; v1.z *= inv; v1.w *= inv;
  od[t] = v0;
  od[t + 256] = v1;
}

// ---------------------------------------------------------------------------
extern "C" void kernel_launch(void* const* d_in, const int* in_sizes, int n_in,
                              void* d_out, int out_size, void* d_ws, size_t ws_size,
                              hipStream_t stream) {
  (void)in_sizes; (void)n_in; (void)out_size; (void)ws_size;
  const float* x   = (const float*)d_in[0];
  const float* Wq  = (const float*)d_in[1];
  const float* Wk  = (const float*)d_in[2];
  const float* Wv  = (const float*)d_in[3];
  const float* Wo  = (const float*)d_in[4];
  const float* sqk = (const float*)d_in[5];
  char* ws = (char*)d_ws;

  constexpr size_t SZX = 8388608ull * 2;  // fp16 x-sized buffer (16 MB)
  constexpr size_t SZW = 4194304ull * 2;  // fp16 weight buffer (8 MB)

  size_t o_xh = 0;
  size_t o_xl = o_xh + SZX;
  size_t o_wq = o_xl + SZX;
  size_t o_wk = o_wq + SZW;
  size_t o_wv = o_wk + SZW;
  size_t o_wo = o_wv + SZW;
  size_t o_qh = o_wo + SZW;
  size_t o_ql = o_qh + SZX;
  size_t o_kh = o_ql + SZX;
  size_t o_v  = o_kh + SZX;
  size_t o_vt = o_v + SZX;
  size_t o_cos = o_vt + SZX;
  size_t o_sin = o_cos + 2048 * 64 * 4;
  // aliases (lifetimes disjoint):
  size_t o_aout = o_wq;  // 16 MB over wq+wk (dead after QK proj... flash runs later)
  size_t o_y    = o_qh;  // 32 MB fp32 over qh+ql (dead after flash)

  _Float16* xh = (_Float16*)(ws + o_xh);
  _Float16* xl = (_Float16*)(ws + o_xl);
  _Float16* wq = (_Float16*)(ws + o_wq);
  _Float16* wk = (_Float16*)(ws + o_wk);
  _Float16* wv = (_Float16*)(ws + o_wv);
  _Float16* wo = (_Float16*)(ws + o_wo);
  _Float16* qh = (_Float16*)(ws + o_qh);
  _Float16* ql = (_Float16*)(ws + o_ql);
  _Float16* kh = (_Float16*)(ws + o_kh);
  _Float16* vt = (_Float16*)(ws + o_vt);
  float* cosT = (float*)(ws + o_cos);
  float* sinT = (float*)(ws + o_sin);
  _Float16* aout = (_Float16*)(ws + o_aout);
  float* y = (float*)(ws + o_y);

  cvt_prep<<<8192, 256, 0, stream>>>((const float4*)x, (const float4*)Wq,
                                     (const float4*)Wk, (const float4*)Wv,
                                     (const float4*)Wo, (half4v*)xh, (half4v*)xl,
                                     (half4v*)wq, (half4v*)wk, (half4v*)wv,
                                     (half4v*)wo, cosT, sinT);

  gemm_qk_f16<<<dim3(16, 16), 512, 0, stream>>>(xh, xl, wq, wk, cosT, sinT,
                                                sqk, qh, ql, kh);
  gemm_v_f16<<<dim3(16, 16), 512, 0, stream>>>(xh, wv, vt);

  flash_attn<<<dim3(32, 16), 256, 0, stream>>>(qh, ql, kh, vt, aout);

  gemm_o_f16<<<dim3(16, 32), 256, 0, stream>>>(aout, wo, y);
  rownorm<<<4096, 256, 0, stream>>>(y, (float*)d_out);
}

// Round 3
// 527.628 us; speedup vs baseline: 1.0155x; 1.0127x over previous
//
#include <hip/hip_runtime.h>

#define DEVFN __device__ __forceinline__

typedef float    floatx4 __attribute__((ext_vector_type(4)));
typedef _Float16 half8   __attribute__((ext_vector_type(8)));
typedef _Float16 half4v  __attribute__((ext_vector_type(4)));

#define MFMA16H(a, b, c) __builtin_amdgcn_mfma_f32_16x16x32_f16((a), (b), (c), 0, 0, 0)

DEVFN void async16(void* lds, const void* g) {
  __builtin_amdgcn_global_load_lds(
      (const __attribute__((address_space(1))) unsigned int*)g,
      (__attribute__((address_space(3))) unsigned int*)lds, 16, 0, 0);
}
DEVFN half8 ld8h(const _Float16* p) { return *(const half8*)p; }

// ---------------------------------------------------------------------------
// prep: x -> fp16 hi/lo split; Wq,Wk,Wv,Wo -> fp16; rope tables (fp64) folded
// ---------------------------------------------------------------------------
__global__ __launch_bounds__(256) void cvt_prep(
    const float4* __restrict__ x, const float4* __restrict__ wq,
    const float4* __restrict__ wk, const float4* __restrict__ wv,
    const float4* __restrict__ wo,
    half4v* __restrict__ xh, half4v* __restrict__ xl,
    half4v* __restrict__ qo, half4v* __restrict__ ko,
    half4v* __restrict__ vo, half4v* __restrict__ oo,
    float* __restrict__ cosT, float* __restrict__ sinT) {
  int i = blockIdx.x * 256 + threadIdx.x;  // grid covers 2097152 float4 of x
  {
    float4 v = x[i];
    half4v h = {(_Float16)v.x, (_Float16)v.y, (_Float16)v.z, (_Float16)v.w};
    half4v l = {(_Float16)(v.x - (float)h.x), (_Float16)(v.y - (float)h.y),
                (_Float16)(v.z - (float)h.z), (_Float16)(v.w - (float)h.w)};
    xh[i] = h;
    xl[i] = l;
  }
  if (i < 1048576) {
    float4 v = wq[i];
    qo[i] = (half4v){(_Float16)v.x, (_Float16)v.y, (_Float16)v.z, (_Float16)v.w};
    v = wk[i];
    ko[i] = (half4v){(_Float16)v.x, (_Float16)v.y, (_Float16)v.z, (_Float16)v.w};
    v = wv[i];
    vo[i] = (half4v){(_Float16)v.x, (_Float16)v.y, (_Float16)v.z, (_Float16)v.w};
    v = wo[i];
    oo[i] = (half4v){(_Float16)v.x, (_Float16)v.y, (_Float16)v.z, (_Float16)v.w};
  }
  if (i < 131072) {  // rope tables: t = i>>6, d = i&63
    int t = i >> 6, d = i & 63;
    double theta = exp(-((double)(2 * d) / 128.0) * log(10000.0));
    double ang = (double)t * theta;
    cosT[i] = (float)cos(ang);
    sinT[i] = (float)sin(ang);
  }
}

// ---------------------------------------------------------------------------
// Q+K projection, fp16 2-pass (x split exact, W fp16-rounded). 256x128 tile,
// BK=32, 512 threads / 8 waves. Wave owns 64 rows x 64 cols per matrix
// (4x4 fragment grid), cols = granules {2c0,2c0+1,2c0+4,2c0+5} so RoPE pairs
// (d, d+64) are wave-local. 2 phases/K-step, 32-MFMA clusters, X 2-buffered,
// W 3-buffered (112 KB LDS, 1 block/CU), counted vmcnt(2) boundary waits.
// Epilogue: RoPE fp32; Q split-fp16 (hi+lo), K single fp16, at [B,NH,T,HD].
// ---------------------------------------------------------------------------
__global__ __launch_bounds__(512, 2) void gemm_qk_f16(
    const _Float16* __restrict__ xhp, const _Float16* __restrict__ xlp,
    const _Float16* __restrict__ wqp, const _Float16* __restrict__ wkp,
    const float* __restrict__ cosT, const float* __restrict__ sinT,
    const float* __restrict__ sqk,
    _Float16* __restrict__ qhi, _Float16* __restrict__ qlo,
    _Float16* __restrict__ khi) {
  constexpr int Kd = 2048, NT = 64;
  const int n0 = blockIdx.x * 128, m0 = blockIdx.y * 256;
  const int tid = threadIdx.x, w = tid >> 6, lane = tid & 63;
  const int quad = lane >> 4, l16 = lane & 15;
  const int c0 = w & 1, rb = w >> 1, rgb = rb * 4;
  const int cgr0 = 2 * c0, cgr1 = 2 * c0 + 1, cgr2 = 2 * c0 + 4, cgr3 = 2 * c0 + 5;

  // LDS (halves): XH[2][8192] XL[2][8192] WQ[3][4096] WK[3][4096] = 112 KB
  __shared__ __align__(16) _Float16 smem[57344];
  _Float16* XH = smem;
  _Float16* XL = smem + 16384;
  _Float16* WQ = smem + 32768;
  _Float16* WK = smem + 45056;

  floatx4 accQ[4][4], accK[4][4];
#pragma unroll
  for (int i = 0; i < 4; i++)
#pragma unroll
    for (int c = 0; c < 4; c++) {
      accQ[i][c] = (floatx4){0.f, 0.f, 0.f, 0.f};
      accK[i][c] = (floatx4){0.f, 0.f, 0.f, 0.f};
    }

  // wave w stages X granules {2w, 2w+1}, W granule w (fragment-linear layout)
  const size_t xg0 = (size_t)(m0 + 32 * w + l16) * Kd + quad * 8;
  const size_t xg1 = xg0 + (size_t)16 * Kd;
  const size_t wg = (size_t)(n0 + 16 * w + l16) * Kd + quad * 8;

#define STAGE_X(T)                                                      \
  {                                                                     \
    const int kk_ = (T) * 32;                                           \
    _Float16* bx_ = XH + ((T) & 1) * 8192;                              \
    _Float16* bl_ = XL + ((T) & 1) * 8192;                              \
    async16(bx_ + (2 * w) * 512, xhp + xg0 + kk_);                      \
    async16(bx_ + (2 * w + 1) * 512, xhp + xg1 + kk_);                  \
    async16(bl_ + (2 * w) * 512, xlp + xg0 + kk_);                      \
    async16(bl_ + (2 * w + 1) * 512, xlp + xg1 + kk_);                  \
  }
#define STAGE_W(T)                                                      \
  {                                                                     \
    const int kk_ = (T) * 32;                                           \
    async16(WQ + ((T) % 3) * 4096 + w * 512, wqp + wg + kk_);           \
    async16(WK + ((T) % 3) * 4096 + w * 512, wkp + wg + kk_);           \
  }

  // prologue: X(0), W(0), W(1) -> wait X0,W0 (newest 2 = W(1) stay in flight)
  STAGE_X(0);
  STAGE_W(0);
  STAGE_W(1);
  asm volatile("s_waitcnt vmcnt(2)" ::: "memory");
  __builtin_amdgcn_s_barrier();

#pragma unroll 1
  for (int t = 0; t < NT; ++t) {
    const _Float16* XH_ = XH + (t & 1) * 8192;
    const _Float16* XL_ = XL + (t & 1) * 8192;
    const _Float16* WQ_ = WQ + (t % 3) * 4096;
    const _Float16* WK_ = WK + (t % 3) * 4096;

    // ---- phase 0: A-frags + Bq; stage X(t+1); 32 MFMA (Q hi+lo) ----
    half8 ah[4], al[4], bq[4];
#pragma unroll
    for (int i = 0; i < 4; i++) {
      ah[i] = ld8h(XH_ + (rgb + i) * 512 + lane * 8);
      al[i] = ld8h(XL_ + (rgb + i) * 512 + lane * 8);
    }
    bq[0] = ld8h(WQ_ + cgr0 * 512 + lane * 8);
    bq[1] = ld8h(WQ_ + cgr1 * 512 + lane * 8);
    bq[2] = ld8h(WQ_ + cgr2 * 512 + lane * 8);
    bq[3] = ld8h(WQ_ + cgr3 * 512 + lane * 8);
    if (t + 1 < NT) STAGE_X(t + 1);
    __builtin_amdgcn_s_barrier();
    asm volatile("s_waitcnt lgkmcnt(0)");
    __builtin_amdgcn_sched_barrier(0);
    __builtin_amdgcn_s_setprio(1);
#pragma unroll
    for (int i = 0; i < 4; i++)
#pragma unroll
      for (int c = 0; c < 4; c++)
        accQ[i][c] = MFMA16H(ah[i], bq[c], accQ[i][c]);
#pragma unroll
    for (int i = 0; i < 4; i++)
#pragma unroll
      for (int c = 0; c < 4; c++)
        accQ[i][c] = MFMA16H(al[i], bq[c], accQ[i][c]);
    __builtin_amdgcn_s_setprio(0);
    __builtin_amdgcn_s_barrier();

    // ---- phase 1: Bk; stage W(t+2); 32 MFMA (K hi+lo) ----
    half8 bk[4];
    bk[0] = ld8h(WK_ + cgr0 * 512 + lane * 8);
    bk[1] = ld8h(WK_ + cgr1 * 512 + lane * 8);
    bk[2] = ld8h(WK_ + cgr2 * 512 + lane * 8);
    bk[3] = ld8h(WK_ + cgr3 * 512 + lane * 8);
    if (t + 2 < NT) STAGE_W(t + 2);
    __builtin_amdgcn_s_barrier();
    asm volatile("s_waitcnt lgkmcnt(0)");
    __builtin_amdgcn_sched_barrier(0);
    __builtin_amdgcn_s_setprio(1);
#pragma unroll
    for (int i = 0; i < 4; i++)
#pragma unroll
      for (int c = 0; c < 4; c++)
        accK[i][c] = MFMA16H(ah[i], bk[c], accK[i][c]);
#pragma unroll
    for (int i = 0; i < 4; i++)
#pragma unroll
      for (int c = 0; c < 4; c++)
        accK[i][c] = MFMA16H(al[i], bk[c], accK[i][c]);
    __builtin_amdgcn_s_setprio(0);

    // boundary: newest 2 outstanding = W(t+2); X(t+1), W(t+1) guaranteed done
    if (t + 2 < NT) {
      asm volatile("s_waitcnt vmcnt(2)" ::: "memory");
    } else {
      asm volatile("s_waitcnt vmcnt(0)" ::: "memory");
    }
    __builtin_amdgcn_s_barrier();
  }
#undef STAGE_X
#undef STAGE_W

  // ---- epilogue: RoPE + store, staged through dead K-loop LDS ----
  _Float16* stH = smem + w * 1152;          // 16 x 72 halves per wave
  _Float16* stL = smem + 9216 + w * 1152;

  const int h = n0 >> 7;
  const int b = m0 >> 11;

#pragma unroll
  for (int rg = 0; rg < 4; rg++) {
    const int tt0 = (m0 & 2047) + rb * 64 + rg * 16;
    const size_t gbase = (((size_t)(b * 16 + h)) * 2048 + tt0) * 128;

    // ---- Q: RoPE + sqk*sqrt(2048)*sqrt(128), split-fp16 ----
#pragma unroll
    for (int cj = 0; cj < 2; cj++) {
      int d = c0 * 32 + cj * 16 + l16;
      float s1 = sqk[h * 128 + d] * 512.0f;
      float s2 = sqk[h * 128 + d + 64] * 512.0f;
#pragma unroll
      for (int r = 0; r < 4; r++) {
        int tq = tt0 + quad * 4 + r;
        float cc = cosT[tq * 64 + d], sn = sinT[tq * 64 + d];
        float xr = accQ[rg][cj][r], xi = accQ[rg][cj + 2][r];
        float o1 = (xr * cc - xi * sn) * s1;
        float o2 = (xr * sn + xi * cc) * s2;
        _Float16 h1 = (_Float16)o1, h2 = (_Float16)o2;
        int rl = quad * 4 + r;
        stH[rl * 72 + cj * 16 + l16] = h1;
        stH[rl * 72 + 32 + cj * 16 + l16] = h2;
        stL[rl * 72 + cj * 16 + l16] = (_Float16)(o1 - (float)h1);
        stL[rl * 72 + 32 + cj * 16 + l16] = (_Float16)(o2 - (float)h2);
      }
    }
#pragma unroll
    for (int it = 0; it < 2; it++) {
      int row = it * 8 + (lane >> 3), pc = (lane & 7) * 8;
      int d = (pc < 32) ? (c0 * 32 + pc) : (64 + c0 * 32 + (pc - 32));
      size_t ga = gbase + (size_t)row * 128 + d;
      *(half8*)(qhi + ga) = ld8h(&stH[row * 72 + pc]);
      *(half8*)(qlo + ga) = ld8h(&stL[row * 72 + pc]);
    }

    // ---- K: RoPE + sqk*sqrt(2048), single fp16 ----
#pragma unroll
    for (int cj = 0; cj < 2; cj++) {
      int d = c0 * 32 + cj * 16 + l16;
      float s1 = sqk[h * 128 + d] * 45.254834f;
      float s2 = sqk[h * 128 + d + 64] * 45.254834f;
#pragma unroll
      for (int r = 0; r < 4; r++) {
        int tq = tt0 + quad * 4 + r;
        float cc = cosT[tq * 64 + d], sn = sinT[tq * 64 + d];
        float xr = accK[rg][cj][r], xi = accK[rg][cj + 2][r];
        int rl = quad * 4 + r;
        stH[rl * 72 + cj * 16 + l16] = (_Float16)((xr * cc - xi * sn) * s1);
        stH[rl * 72 + 32 + cj * 16 + l16] = (_Float16)((xr * sn + xi * cc) * s2);
      }
    }
#pragma unroll
    for (int it = 0; it < 2; it++) {
      int row = it * 8 + (lane >> 3), pc = (lane & 7) * 8;
      int d = (pc < 32) ? (c0 * 32 + pc) : (64 + c0 * 32 + (pc - 32));
      *(half8*)(khi + gbase + (size_t)row * 128 + d) = ld8h(&stH[row * 72 + pc]);
    }
  }
}

// ---------------------------------------------------------------------------
// V projection, fp16 1-pass (x hi only). Same 256x128 tiling, single phase
// per K-step (16-MFMA cluster), X 2-buffered + Wv 3-buffered (56 KB LDS,
// 2 blocks/CU), counted vmcnt(1). Epilogue writes vt = V^T directly
// ([BH][HD][T]) via LDS transpose staging.
// ---------------------------------------------------------------------------
__global__ __launch_bounds__(512, 2) void gemm_v_f16(
    const _Float16* __restrict__ xhp, const _Float16* __restrict__ wvp,
    _Float16* __restrict__ vt) {
  constexpr int Kd = 2048, NT = 64;
  const int n0 = blockIdx.x * 128, m0 = blockIdx.y * 256;
  const int tid = threadIdx.x, w = tid >> 6, lane = tid & 63;
  const int quad = lane >> 4, l16 = lane & 15;
  const int c0 = w & 1, rb = w >> 1, rgb = rb * 4;

  // LDS (halves): XH[2][8192] WV[3][4096] = 56 KB
  __shared__ __align__(16) _Float16 smem[28672];
  _Float16* XH = smem;
  _Float16* WV = smem + 16384;

  floatx4 accV[4][4];
#pragma unroll
  for (int i = 0; i < 4; i++)
#pragma unroll
    for (int c = 0; c < 4; c++) accV[i][c] = (floatx4){0.f, 0.f, 0.f, 0.f};

  const size_t xg0 = (size_t)(m0 + 32 * w + l16) * Kd + quad * 8;
  const size_t xg1 = xg0 + (size_t)16 * Kd;
  const size_t wg = (size_t)(n0 + 16 * w + l16) * Kd + quad * 8;

#define STAGE_XV(T)                                                     \
  {                                                                     \
    const int kk_ = (T) * 32;                                           \
    _Float16* bx_ = XH + ((T) & 1) * 8192;                              \
    async16(bx_ + (2 * w) * 512, xhp + xg0 + kk_);                      \
    async16(bx_ + (2 * w + 1) * 512, xhp + xg1 + kk_);                  \
  }
#define STAGE_WV(T)                                                     \
  { async16(WV + ((T) % 3) * 4096 + w * 512, wvp + wg + (T) * 32); }

  STAGE_XV(0);
  STAGE_WV(0);
  STAGE_WV(1);
  asm volatile("s_waitcnt vmcnt(1)" ::: "memory");
  __builtin_amdgcn_s_barrier();

#pragma unroll 1
  for (int t = 0; t < NT; ++t) {
    const _Float16* XH_ = XH + (t & 1) * 8192;
    const _Float16* WV_ = WV + (t % 3) * 4096;

    half8 ah[4], bv[4];
#pragma unroll
    for (int i = 0; i < 4; i++)
      ah[i] = ld8h(XH_ + (rgb + i) * 512 + lane * 8);
#pragma unroll
    for (int c = 0; c < 4; c++)
      bv[c] = ld8h(WV_ + (4 * c0 + c) * 512 + lane * 8);
    if (t + 1 < NT) STAGE_XV(t + 1);
    if (t + 2 < NT) STAGE_WV(t + 2);
    __builtin_amdgcn_s_barrier();
    asm volatile("s_waitcnt lgkmcnt(0)");
    __builtin_amdgcn_sched_barrier(0);
    __builtin_amdgcn_s_setprio(1);
#pragma unroll
    for (int i = 0; i < 4; i++)
#pragma unroll
      for (int c = 0; c < 4; c++)
        accV[i][c] = MFMA16H(ah[i], bv[c], accV[i][c]);
    __builtin_amdgcn_s_setprio(0);
    if (t + 2 < NT) {
      asm volatile("s_waitcnt vmcnt(1)" ::: "memory");
    } else {
      asm volatile("s_waitcnt vmcnt(0)" ::: "memory");
    }
    __builtin_amdgcn_s_barrier();
  }
#undef STAGE_XV
#undef STAGE_WV

  // ---- epilogue: write vt[bh][d][t] via per-wave LDS transpose staging ----
  _Float16* stV = smem + w * 1024;  // [64 d][16 t] halves per wave

  const int h = n0 >> 7;
  const int b = m0 >> 11;
  const int bh = b * 16 + h;

#pragma unroll
  for (int rg = 0; rg < 4; rg++) {
    const int tt0 = (m0 & 2047) + rb * 64 + rg * 16;
#pragma unroll
    for (int c = 0; c < 4; c++)
#pragma unroll
      for (int r = 0; r < 4; r++)
        stV[(c * 16 + l16) * 16 + quad * 4 + r] = (_Float16)accV[rg][c][r];
#pragma unroll
    for (int it = 0; it < 2; it++) {
      int dl = it * 32 + (lane >> 1), th = (lane & 1) * 8;
      int dh = c0 * 64 + dl;
      size_t ga = ((size_t)bh * 128 + dh) * 2048 + tt0 + th;
      *(half8*)(vt + ga) = ld8h(&stV[dl * 16 + th]);
    }
  }
}

// ---------------------------------------------------------------------------
// flash attention: block = (bh, pair p). Each block does q-tiles {p, 15-p}
// sequentially -> uniform 34 k-tiles/block (causal load-balance). 4 waves x
// 32 rows, K-tiles of 64, K/V LDS double-buffered. Softmax restructured:
// batched 16-lane shuffle reductions (8 rows in flight, ILP across rows) +
// defer-max (THR=8: skip max-reduce + O-rescale when tile max within
// threshold of running max). setprio(1) around MFMA clusters.
// QK^T 2-pass (q split exact, k fp16-rounded), online softmax fp32, PV fp16.
// ---------------------------------------------------------------------------
__global__ __launch_bounds__(256, 2) void flash_attn(
    const _Float16* __restrict__ qhp, const _Float16* __restrict__ qlp,
    const _Float16* __restrict__ khp,
    const _Float16* __restrict__ vtp, _Float16* __restrict__ aout) {
  constexpr int T = 2048, HD = 128;
  const int bh = blockIdx.x, p = blockIdx.y;
  const int tid = threadIdx.x, w = tid >> 6, lane = tid & 63;
  const int quad = lane >> 4, l16 = lane & 15;

  __shared__ __align__(16) _Float16 Kh[2][8192];   // 64 x 128, granule layout
  __shared__ __align__(16) _Float16 Vt[2][8192];   // 128 x 64, granule layout
  __shared__ __align__(16) _Float16 Pb[4][16 * 72];  // per-wave, padded

  const size_t qkbase = (size_t)bh * T * HD;
  const size_t vbase = (size_t)bh * HD * T;

  auto stageKV = [&](int kt, int set) {
    const int s0 = kt * 64;
    for (int c = w; c < 16; c += 4) {
      int tt = c >> 2, ss = c & 3;
      size_t go = qkbase + (size_t)(s0 + tt * 16 + l16) * HD + ss * 32 + quad * 8;
      async16(&Kh[set][c * 512], khp + go);
      int dt = c >> 1, vs = c & 1;
      size_t vo = vbase + (size_t)(dt * 16 + l16) * T + s0 + vs * 32 + quad * 8;
      async16(&Vt[set][c * 512], vtp + vo);
    }
  };

#pragma unroll 1
  for (int half = 0; half < 2; ++half) {
    const int qt = half ? (15 - p) : p;
    const int q0 = qt * 128;

    half8 qh[2][4], ql[2][4];
#pragma unroll
    for (int i = 0; i < 2; i++)
#pragma unroll
      for (int s = 0; s < 4; s++) {
        size_t off = qkbase + (size_t)(q0 + w * 32 + i * 16 + l16) * HD + s * 32 + quad * 8;
        qh[i][s] = *(const half8*)(qhp + off);
        ql[i][s] = *(const half8*)(qlp + off);
      }

    floatx4 o[2][8];
#pragma unroll
    for (int i = 0; i < 2; i++)
#pragma unroll
      for (int dt = 0; dt < 8; dt++) o[i][dt] = (floatx4){0.f, 0.f, 0.f, 0.f};
    float mrow[2][4], lrow[2][4];
#pragma unroll
    for (int i = 0; i < 2; i++)
#pragma unroll
      for (int r = 0; r < 4; r++) { mrow[i][r] = -3e38f; lrow[i][r] = 0.f; }

    const int ntiles = qt * 2 + 2;

    stageKV(0, 0);
    __syncthreads();

#pragma unroll 1
    for (int kt = 0; kt < ntiles; ++kt) {
      const int s0 = kt * 64;
      const int set = kt & 1;
      if (kt + 1 < ntiles) stageKV(kt + 1, set ^ 1);

      floatx4 S[2][4];
#pragma unroll
      for (int i = 0; i < 2; i++)
#pragma unroll
        for (int j = 0; j < 4; j++) S[i][j] = (floatx4){0.f, 0.f, 0.f, 0.f};

      __builtin_amdgcn_s_setprio(1);
#pragma unroll
      for (int s = 0; s < 4; s++) {
#pragma unroll
        for (int j = 0; j < 4; j++) {
          half8 kh = ld8h(&Kh[set][(j * 4 + s) * 512 + lane * 8]);
          S[0][j] = MFMA16H(qh[0][s], kh, S[0][j]);
          S[1][j] = MFMA16H(qh[1][s], kh, S[1][j]);
          S[0][j] = MFMA16H(ql[0][s], kh, S[0][j]);
          S[1][j] = MFMA16H(ql[1][s], kh, S[1][j]);
        }
      }
      __builtin_amdgcn_s_setprio(0);

      if (s0 + 63 > q0) {  // causal mask (near-diagonal tiles only)
#pragma unroll
        for (int i = 0; i < 2; i++) {
          int rb = q0 + w * 32 + i * 16 + quad * 4;
#pragma unroll
          for (int j = 0; j < 4; j++) {
            int cg = s0 + j * 16 + l16;
#pragma unroll
            for (int r = 0; r < 4; r++)
              if (cg > rb + r) S[i][j][r] = -3e38f;
          }
        }
      }

      // ---- softmax: batched reductions + defer-max (THR=8) ----
      float lm[2][4];
#pragma unroll
      for (int i = 0; i < 2; i++)
#pragma unroll
        for (int r = 0; r < 4; r++)
          lm[i][r] = fmaxf(fmaxf(S[i][0][r], S[i][1][r]),
                           fmaxf(S[i][2][r], S[i][3][r]));

      bool ok = true;
#pragma unroll
      for (int i = 0; i < 2; i++)
#pragma unroll
        for (int r = 0; r < 4; r++)
          ok = ok && (lm[i][r] <= mrow[i][r] + 8.0f);

      if (!__all(ok ? 1 : 0)) {  // slow path: wave-uniform
        // batched 16-lane max reduce (8 independent chains per step)
#pragma unroll
        for (int d = 1; d < 16; d <<= 1)
#pragma unroll
          for (int i = 0; i < 2; i++)
#pragma unroll
            for (int r = 0; r < 4; r++)
              lm[i][r] = fmaxf(lm[i][r], __shfl_xor(lm[i][r], d, 64));
#pragma unroll
        for (int i = 0; i < 2; i++)
#pragma unroll
          for (int r = 0; r < 4; r++) {
            float mnew = fmaxf(mrow[i][r], lm[i][r]);
            float al = __expf(mrow[i][r] - mnew);
            mrow[i][r] = mnew;
            lrow[i][r] *= al;
#pragma unroll
            for (int dt = 0; dt < 8; dt++) o[i][dt][r] *= al;
          }
      }

      float rs[2][4];
#pragma unroll
      for (int i = 0; i < 2; i++)
#pragma unroll
        for (int r = 0; r < 4; r++) {
          float e0 = __expf(S[i][0][r] - mrow[i][r]);
          float e1 = __expf(S[i][1][r] - mrow[i][r]);
          float e2 = __expf(S[i][2][r] - mrow[i][r]);
          float e3 = __expf(S[i][3][r] - mrow[i][r]);
          S[i][0][r] = e0; S[i][1][r] = e1; S[i][2][r] = e2; S[i][3][r] = e3;
          rs[i][r] = (e0 + e1) + (e2 + e3);
        }
      // batched 16-lane sum reduce
#pragma unroll
      for (int d = 1; d < 16; d <<= 1)
#pragma unroll
        for (int i = 0; i < 2; i++)
#pragma unroll
          for (int r = 0; r < 4; r++)
            rs[i][r] += __shfl_xor(rs[i][r], d, 64);
#pragma unroll
      for (int i = 0; i < 2; i++)
#pragma unroll
        for (int r = 0; r < 4; r++) lrow[i][r] += rs[i][r];

      // P -> LDS (A-fragment transform); per-wave buffer, DS in-order
      half8 pf[2][2];
#pragma unroll
      for (int i = 0; i < 2; i++) {
#pragma unroll
        for (int r = 0; r < 4; r++)
#pragma unroll
          for (int j = 0; j < 4; j++)
            Pb[w][(quad * 4 + r) * 72 + j * 16 + l16] = (_Float16)S[i][j][r];
        pf[i][0] = ld8h(&Pb[w][l16 * 72 + quad * 8]);
        pf[i][1] = ld8h(&Pb[w][l16 * 72 + 32 + quad * 8]);
      }

      __builtin_amdgcn_s_setprio(1);
#pragma unroll
      for (int dt = 0; dt < 8; dt++) {
#pragma unroll
        for (int s = 0; s < 2; s++) {
          half8 vf = ld8h(&Vt[set][(dt * 2 + s) * 512 + lane * 8]);
          o[0][dt] = MFMA16H(pf[0][s], vf, o[0][dt]);
          o[1][dt] = MFMA16H(pf[1][s], vf, o[1][dt]);
        }
      }
      __builtin_amdgcn_s_setprio(0);
      __syncthreads();
    }

    const int b = bh >> 4, h = bh & 15;
#pragma unroll
    for (int i = 0; i < 2; i++) {
#pragma unroll
      for (int r = 0; r < 4; r++) {
        int trow = q0 + w * 32 + i * 16 + quad * 4 + r;
        float linv = 1.0f / lrow[i][r];
        size_t base = ((size_t)(b * T + trow)) * 2048 + h * 128;
#pragma unroll
        for (int dt = 0; dt < 8; dt++)
          aout[base + dt * 16 + l16] = (_Float16)(o[i][dt][r] * linv);
      }
    }
  }
}

// ---------------------------------------------------------------------------
// O projection: y = aout @ Wo^T, fp16 in, fp32 out. 128x128 tile, BK=64.
// ---------------------------------------------------------------------------
__global__ __launch_bounds__(256, 2) void gemm_o_f16(
    const _Float16* __restrict__ A, const _Float16* __restrict__ B,
    float* __restrict__ outF) {
  constexpr int Kd = 2048;
  constexpr int Nd = 2048;
  const int n0 = blockIdx.x * 128, m0 = blockIdx.y * 128;
  const int tid = threadIdx.x, w = tid >> 6, lane = tid & 63;
  const int quad = lane >> 4, l16 = lane & 15;

  __shared__ __align__(16) _Float16 As[8192];  // two 32-k sub-tiles
  __shared__ __align__(16) _Float16 Bs[8192];

  floatx4 acc[2][8];
#pragma unroll
  for (int i = 0; i < 2; i++)
#pragma unroll
    for (int j = 0; j < 8; j++) acc[i][j] = (floatx4){0.f, 0.f, 0.f, 0.f};

  const int t0 = 2 * w, t1 = 2 * w + 1;
  const size_t ao0 = (size_t)(m0 + t0 * 16 + l16) * Kd + quad * 8;
  const size_t ao1 = (size_t)(m0 + t1 * 16 + l16) * Kd + quad * 8;
  const size_t bo0 = (size_t)(n0 + t0 * 16 + l16) * Kd + quad * 8;
  const size_t bo1 = (size_t)(n0 + t1 * 16 + l16) * Kd + quad * 8;

  for (int k0 = 0; k0 < Kd; k0 += 64) {
    __syncthreads();
    async16(&As[t0 * 512], A + ao0 + k0);
    async16(&As[t1 * 512], A + ao1 + k0);
    async16(&As[4096 + t0 * 512], A + ao0 + k0 + 32);
    async16(&As[4096 + t1 * 512], A + ao1 + k0 + 32);
    async16(&Bs[t0 * 512], B + bo0 + k0);
    async16(&Bs[t1 * 512], B + bo1 + k0);
    async16(&Bs[4096 + t0 * 512], B + bo0 + k0 + 32);
    async16(&Bs[4096 + t1 * 512], B + bo1 + k0 + 32);
    __syncthreads();
    half8 a00 = ld8h(&As[t0 * 512 + lane * 8]);
    half8 a10 = ld8h(&As[t1 * 512 + lane * 8]);
    half8 a01 = ld8h(&As[4096 + t0 * 512 + lane * 8]);
    half8 a11 = ld8h(&As[4096 + t1 * 512 + lane * 8]);
#pragma unroll
    for (int j = 0; j < 8; j++) {
      half8 b0 = ld8h(&Bs[j * 512 + lane * 8]);
      acc[0][j] = MFMA16H(a00, b0, acc[0][j]);
      acc[1][j] = MFMA16H(a10, b0, acc[1][j]);
      half8 b1 = ld8h(&Bs[4096 + j * 512 + lane * 8]);
      acc[0][j] = MFMA16H(a01, b1, acc[0][j]);
      acc[1][j] = MFMA16H(a11, b1, acc[1][j]);
    }
  }

#pragma unroll
  for (int i = 0; i < 2; i++) {
    int rbase = m0 + (2 * w + i) * 16 + quad * 4;
#pragma unroll
    for (int j = 0; j < 8; j++) {
      int col = n0 + j * 16 + l16;
#pragma unroll
      for (int r = 0; r < 4; r++)
        outF[(size_t)(rbase + r) * Nd + col] = acc[i][j][r];
    }
  }
}

// ---------------------------------------------------------------------------
// per-row L2 normalize: out = y / max(||y||, 1e-12)
// ---------------------------------------------------------------------------
__global__ __launch_bounds__(256) void rownorm(const float* __restrict__ y,
                                               float* __restrict__ out) {
  int row = blockIdx.x;
  const float4* yr = (const float4*)(y + (size_t)row * 2048);
  float4* od = (float4*)(out + (size_t)row * 2048);
  int t = threadIdx.x;
  float4 v0 = yr[t], v1 = yr[t + 256];
  float ss = v0.x * v0.x + v0.y * v0.y + v0.z * v0.z + v0.w * v0.w +
             v1.x * v1.x + v1.y * v1.y + v1.z * v1.z + v1.w * v1.w;
#pragma unroll
  for (int d = 1; d < 64; d <<= 1) ss += __shfl_xor(ss, d, 64);
  __shared__ float red[4];
  if ((t & 63) == 0) red[t >> 6] = ss;
  __syncthreads();
  float tot = red[0] + red[1] + red[2] + red[3];
  float inv = 1.0f / fmaxf(sqrtf(tot), 1e-12f);
  v0.x *= inv; v0.y *= inv; v0.z *= inv; v0.w *= inv;
  v1.x *= inv; v1.y *= inv; v1.z *= inv; v1.w *= inv;
  od[t] = v0;
  od[t + 256] = v1;
}

// ---------------------------------------------------------------------------
extern "C" void kernel_launch(void* const* d_in, const int* in_sizes, int n_in,
                              void* d_out, int out_size, void* d_ws, size_t ws_size,
                              hipStream_t stream) {
  (void)in_sizes; (void)n_in; (void)out_size; (void)ws_size;
  const float* x   = (const float*)d_in[0];
  const float* Wq  = (const float*)d_in[1];
  const float* Wk  = (const float*)d_in[2];
  const float* Wv  = (const float*)d_in[3];
  const float* Wo  = (const float*)d_in[4];
  const float* sqk = (const float*)d_in[5];
  char* ws = (char*)d_ws;

  constexpr size_t SZX = 8388608ull * 2;  // fp16 x-sized buffer (16 MB)
  constexpr size_t SZW = 4194304ull * 2;  // fp16 weight buffer (8 MB)

  size_t o_xh = 0;
  size_t o_xl = o_xh + SZX;
  size_t o_wq = o_xl + SZX;
  size_t o_wk = o_wq + SZW;
  size_t o_wv = o_wk + SZW;
  size_t o_wo = o_wv + SZW;
  size_t o_qh = o_wo + SZW;
  size_t o_ql = o_qh + SZX;
  size_t o_kh = o_ql + SZX;
  size_t o_v  = o_kh + SZX;
  size_t o_vt = o_v + SZX;
  size_t o_cos = o_vt + SZX;
  size_t o_sin = o_cos + 2048 * 64 * 4;
  // aliases (lifetimes disjoint):
  size_t o_aout = o_wq;  // 16 MB over wq+wk (dead after QK proj)
  size_t o_y    = o_qh;  // 32 MB fp32 over qh+ql (dead after flash)

  _Float16* xh = (_Float16*)(ws + o_xh);
  _Float16* xl = (_Float16*)(ws + o_xl);
  _Float16* wq = (_Float16*)(ws + o_wq);
  _Float16* wk = (_Float16*)(ws + o_wk);
  _Float16* wv = (_Float16*)(ws + o_wv);
  _Float16* wo = (_Float16*)(ws + o_wo);
  _Float16* qh = (_Float16*)(ws + o_qh);
  _Float16* ql = (_Float16*)(ws + o_ql);
  _Float16* kh = (_Float16*)(ws + o_kh);
  _Float16* vt = (_Float16*)(ws + o_vt);
  float* cosT = (float*)(ws + o_cos);
  float* sinT = (float*)(ws + o_sin);
  _Float16* aout = (_Float16*)(ws + o_aout);
  float* y = (float*)(ws + o_y);

  cvt_prep<<<8192, 256, 0, stream>>>((const float4*)x, (const float4*)Wq,
                                     (const float4*)Wk, (const float4*)Wv,
                                     (const float4*)Wo, (half4v*)xh, (half4v*)xl,
                                     (half4v*)wq, (half4v*)wk, (half4v*)wv,
                                     (half4v*)wo, cosT, sinT);

  gemm_qk_f16<<<dim3(16, 16), 512, 0, stream>>>(xh, xl, wq, wk, cosT, sinT,
                                                sqk, qh, ql, kh);
  gemm_v_f16<<<dim3(16, 16), 512, 0, stream>>>(xh, wv, vt);

  flash_attn<<<dim3(32, 8), 256, 0, stream>>>(qh, ql, kh, vt, aout);

  gemm_o_f16<<<dim3(16, 32), 256, 0, stream>>>(aout, wo, y);
  rownorm<<<4096, 256, 0, stream>>>(y, (float*)d_out);
}

// Round 4
// 496.532 us; speedup vs baseline: 1.0791x; 1.0626x over previous
//
#include <hip/hip_runtime.h>

#define DEVFN __device__ __forceinline__

typedef float    floatx4 __attribute__((ext_vector_type(4)));
typedef _Float16 half8   __attribute__((ext_vector_type(8)));
typedef _Float16 half4v  __attribute__((ext_vector_type(4)));

#define MFMA16H(a, b, c) __builtin_amdgcn_mfma_f32_16x16x32_f16((a), (b), (c), 0, 0, 0)

DEVFN void async16(void* lds, const void* g) {
  __builtin_amdgcn_global_load_lds(
      (const __attribute__((address_space(1))) unsigned int*)g,
      (__attribute__((address_space(3))) unsigned int*)lds, 16, 0, 0);
}
DEVFN half8 ld8h(const _Float16* p) { return *(const half8*)p; }

// ---------------------------------------------------------------------------
// prep: x -> fp16 hi/lo split; Wq,Wk,Wv,Wo -> fp16; rope tables (fp64) folded
// ---------------------------------------------------------------------------
__global__ __launch_bounds__(256) void cvt_prep(
    const float4* __restrict__ x, const float4* __restrict__ wq,
    const float4* __restrict__ wk, const float4* __restrict__ wv,
    const float4* __restrict__ wo,
    half4v* __restrict__ xh, half4v* __restrict__ xl,
    half4v* __restrict__ qo, half4v* __restrict__ ko,
    half4v* __restrict__ vo, half4v* __restrict__ oo,
    float* __restrict__ cosT, float* __restrict__ sinT) {
  int i = blockIdx.x * 256 + threadIdx.x;  // grid covers 2097152 float4 of x
  {
    float4 v = x[i];
    half4v h = {(_Float16)v.x, (_Float16)v.y, (_Float16)v.z, (_Float16)v.w};
    half4v l = {(_Float16)(v.x - (float)h.x), (_Float16)(v.y - (float)h.y),
                (_Float16)(v.z - (float)h.z), (_Float16)(v.w - (float)h.w)};
    xh[i] = h;
    xl[i] = l;
  }
  if (i < 1048576) {
    float4 v = wq[i];
    qo[i] = (half4v){(_Float16)v.x, (_Float16)v.y, (_Float16)v.z, (_Float16)v.w};
    v = wk[i];
    ko[i] = (half4v){(_Float16)v.x, (_Float16)v.y, (_Float16)v.z, (_Float16)v.w};
    v = wv[i];
    vo[i] = (half4v){(_Float16)v.x, (_Float16)v.y, (_Float16)v.z, (_Float16)v.w};
    v = wo[i];
    oo[i] = (half4v){(_Float16)v.x, (_Float16)v.y, (_Float16)v.z, (_Float16)v.w};
  }
  if (i < 131072) {  // rope tables: t = i>>6, d = i&63
    int t = i >> 6, d = i & 63;
    double theta = exp(-((double)(2 * d) / 128.0) * log(10000.0));
    double ang = (double)t * theta;
    cosT[i] = (float)cos(ang);
    sinT[i] = (float)sin(ang);
  }
}

// ---------------------------------------------------------------------------
// Q+K projection, fp16 2-pass (x split exact, W fp16-rounded). 256x128 tile,
// BK=32, 512 threads / 8 waves. Wave owns 64 rows x 64 cols per matrix
// (4x4 fragment grid), cols = granules {2c0,2c0+1,2c0+4,2c0+5} so RoPE pairs
// (d, d+64) are wave-local. 2 phases/K-step, 32-MFMA clusters, X 2-buffered,
// W 3-buffered (112 KB LDS, 1 block/CU), counted vmcnt(2) boundary waits.
// Epilogue: RoPE fp32; Q split-fp16 (hi+lo), K single fp16, at [B,NH,T,HD].
// ---------------------------------------------------------------------------
__global__ __launch_bounds__(512, 2) void gemm_qk_f16(
    const _Float16* __restrict__ xhp, const _Float16* __restrict__ xlp,
    const _Float16* __restrict__ wqp, const _Float16* __restrict__ wkp,
    const float* __restrict__ cosT, const float* __restrict__ sinT,
    const float* __restrict__ sqk,
    _Float16* __restrict__ qhi, _Float16* __restrict__ qlo,
    _Float16* __restrict__ khi) {
  constexpr int Kd = 2048, NT = 64;
  const int n0 = blockIdx.x * 128, m0 = blockIdx.y * 256;
  const int tid = threadIdx.x, w = tid >> 6, lane = tid & 63;
  const int quad = lane >> 4, l16 = lane & 15;
  const int c0 = w & 1, rb = w >> 1, rgb = rb * 4;
  const int cgr0 = 2 * c0, cgr1 = 2 * c0 + 1, cgr2 = 2 * c0 + 4, cgr3 = 2 * c0 + 5;

  // LDS (halves): XH[2][8192] XL[2][8192] WQ[3][4096] WK[3][4096] = 112 KB
  __shared__ __align__(16) _Float16 smem[57344];
  _Float16* XH = smem;
  _Float16* XL = smem + 16384;
  _Float16* WQ = smem + 32768;
  _Float16* WK = smem + 45056;

  floatx4 accQ[4][4], accK[4][4];
#pragma unroll
  for (int i = 0; i < 4; i++)
#pragma unroll
    for (int c = 0; c < 4; c++) {
      accQ[i][c] = (floatx4){0.f, 0.f, 0.f, 0.f};
      accK[i][c] = (floatx4){0.f, 0.f, 0.f, 0.f};
    }

  // wave w stages X granules {2w, 2w+1}, W granule w (fragment-linear layout)
  const size_t xg0 = (size_t)(m0 + 32 * w + l16) * Kd + quad * 8;
  const size_t xg1 = xg0 + (size_t)16 * Kd;
  const size_t wg = (size_t)(n0 + 16 * w + l16) * Kd + quad * 8;

#define STAGE_X(T)                                                      \
  {                                                                     \
    const int kk_ = (T) * 32;                                           \
    _Float16* bx_ = XH + ((T) & 1) * 8192;                              \
    _Float16* bl_ = XL + ((T) & 1) * 8192;                              \
    async16(bx_ + (2 * w) * 512, xhp + xg0 + kk_);                      \
    async16(bx_ + (2 * w + 1) * 512, xhp + xg1 + kk_);                  \
    async16(bl_ + (2 * w) * 512, xlp + xg0 + kk_);                      \
    async16(bl_ + (2 * w + 1) * 512, xlp + xg1 + kk_);                  \
  }
#define STAGE_W(T)                                                      \
  {                                                                     \
    const int kk_ = (T) * 32;                                           \
    async16(WQ + ((T) % 3) * 4096 + w * 512, wqp + wg + kk_);           \
    async16(WK + ((T) % 3) * 4096 + w * 512, wkp + wg + kk_);           \
  }

  // prologue: X(0), W(0), W(1) -> wait X0,W0 (newest 2 = W(1) stay in flight)
  STAGE_X(0);
  STAGE_W(0);
  STAGE_W(1);
  asm volatile("s_waitcnt vmcnt(2)" ::: "memory");
  __builtin_amdgcn_s_barrier();

#pragma unroll 1
  for (int t = 0; t < NT; ++t) {
    const _Float16* XH_ = XH + (t & 1) * 8192;
    const _Float16* XL_ = XL + (t & 1) * 8192;
    const _Float16* WQ_ = WQ + (t % 3) * 4096;
    const _Float16* WK_ = WK + (t % 3) * 4096;

    // ---- phase 0: A-frags + Bq; stage X(t+1); 32 MFMA (Q hi+lo) ----
    half8 ah[4], al[4], bq[4];
#pragma unroll
    for (int i = 0; i < 4; i++) {
      ah[i] = ld8h(XH_ + (rgb + i) * 512 + lane * 8);
      al[i] = ld8h(XL_ + (rgb + i) * 512 + lane * 8);
    }
    bq[0] = ld8h(WQ_ + cgr0 * 512 + lane * 8);
    bq[1] = ld8h(WQ_ + cgr1 * 512 + lane * 8);
    bq[2] = ld8h(WQ_ + cgr2 * 512 + lane * 8);
    bq[3] = ld8h(WQ_ + cgr3 * 512 + lane * 8);
    if (t + 1 < NT) STAGE_X(t + 1);
    __builtin_amdgcn_s_barrier();
    asm volatile("s_waitcnt lgkmcnt(0)");
    __builtin_amdgcn_sched_barrier(0);
    __builtin_amdgcn_s_setprio(1);
#pragma unroll
    for (int i = 0; i < 4; i++)
#pragma unroll
      for (int c = 0; c < 4; c++)
        accQ[i][c] = MFMA16H(ah[i], bq[c], accQ[i][c]);
#pragma unroll
    for (int i = 0; i < 4; i++)
#pragma unroll
      for (int c = 0; c < 4; c++)
        accQ[i][c] = MFMA16H(al[i], bq[c], accQ[i][c]);
    __builtin_amdgcn_s_setprio(0);
    __builtin_amdgcn_s_barrier();

    // ---- phase 1: Bk; stage W(t+2); 32 MFMA (K hi+lo) ----
    half8 bk[4];
    bk[0] = ld8h(WK_ + cgr0 * 512 + lane * 8);
    bk[1] = ld8h(WK_ + cgr1 * 512 + lane * 8);
    bk[2] = ld8h(WK_ + cgr2 * 512 + lane * 8);
    bk[3] = ld8h(WK_ + cgr3 * 512 + lane * 8);
    if (t + 2 < NT) STAGE_W(t + 2);
    __builtin_amdgcn_s_barrier();
    asm volatile("s_waitcnt lgkmcnt(0)");
    __builtin_amdgcn_sched_barrier(0);
    __builtin_amdgcn_s_setprio(1);
#pragma unroll
    for (int i = 0; i < 4; i++)
#pragma unroll
      for (int c = 0; c < 4; c++)
        accK[i][c] = MFMA16H(ah[i], bk[c], accK[i][c]);
#pragma unroll
    for (int i = 0; i < 4; i++)
#pragma unroll
      for (int c = 0; c < 4; c++)
        accK[i][c] = MFMA16H(al[i], bk[c], accK[i][c]);
    __builtin_amdgcn_s_setprio(0);

    // boundary: newest 2 outstanding = W(t+2); X(t+1), W(t+1) guaranteed done
    if (t + 2 < NT) {
      asm volatile("s_waitcnt vmcnt(2)" ::: "memory");
    } else {
      asm volatile("s_waitcnt vmcnt(0)" ::: "memory");
    }
    __builtin_amdgcn_s_barrier();
  }
#undef STAGE_X
#undef STAGE_W

  // ---- epilogue: RoPE + store, staged through dead K-loop LDS ----
  _Float16* stH = smem + w * 1152;          // 16 x 72 halves per wave
  _Float16* stL = smem + 9216 + w * 1152;

  const int h = n0 >> 7;
  const int b = m0 >> 11;

#pragma unroll
  for (int rg = 0; rg < 4; rg++) {
    const int tt0 = (m0 & 2047) + rb * 64 + rg * 16;
    const size_t gbase = (((size_t)(b * 16 + h)) * 2048 + tt0) * 128;

    // ---- Q: RoPE + sqk*sqrt(2048)*sqrt(128), split-fp16 ----
#pragma unroll
    for (int cj = 0; cj < 2; cj++) {
      int d = c0 * 32 + cj * 16 + l16;
      float s1 = sqk[h * 128 + d] * 512.0f;
      float s2 = sqk[h * 128 + d + 64] * 512.0f;
#pragma unroll
      for (int r = 0; r < 4; r++) {
        int tq = tt0 + quad * 4 + r;
        float cc = cosT[tq * 64 + d], sn = sinT[tq * 64 + d];
        float xr = accQ[rg][cj][r], xi = accQ[rg][cj + 2][r];
        float o1 = (xr * cc - xi * sn) * s1;
        float o2 = (xr * sn + xi * cc) * s2;
        _Float16 h1 = (_Float16)o1, h2 = (_Float16)o2;
        int rl = quad * 4 + r;
        stH[rl * 72 + cj * 16 + l16] = h1;
        stH[rl * 72 + 32 + cj * 16 + l16] = h2;
        stL[rl * 72 + cj * 16 + l16] = (_Float16)(o1 - (float)h1);
        stL[rl * 72 + 32 + cj * 16 + l16] = (_Float16)(o2 - (float)h2);
      }
    }
#pragma unroll
    for (int it = 0; it < 2; it++) {
      int row = it * 8 + (lane >> 3), pc = (lane & 7) * 8;
      int d = (pc < 32) ? (c0 * 32 + pc) : (64 + c0 * 32 + (pc - 32));
      size_t ga = gbase + (size_t)row * 128 + d;
      *(half8*)(qhi + ga) = ld8h(&stH[row * 72 + pc]);
      *(half8*)(qlo + ga) = ld8h(&stL[row * 72 + pc]);
    }

    // ---- K: RoPE + sqk*sqrt(2048), single fp16 ----
#pragma unroll
    for (int cj = 0; cj < 2; cj++) {
      int d = c0 * 32 + cj * 16 + l16;
      float s1 = sqk[h * 128 + d] * 45.254834f;
      float s2 = sqk[h * 128 + d + 64] * 45.254834f;
#pragma unroll
      for (int r = 0; r < 4; r++) {
        int tq = tt0 + quad * 4 + r;
        float cc = cosT[tq * 64 + d], sn = sinT[tq * 64 + d];
        float xr = accK[rg][cj][r], xi = accK[rg][cj + 2][r];
        int rl = quad * 4 + r;
        stH[rl * 72 + cj * 16 + l16] = (_Float16)((xr * cc - xi * sn) * s1);
        stH[rl * 72 + 32 + cj * 16 + l16] = (_Float16)((xr * sn + xi * cc) * s2);
      }
    }
#pragma unroll
    for (int it = 0; it < 2; it++) {
      int row = it * 8 + (lane >> 3), pc = (lane & 7) * 8;
      int d = (pc < 32) ? (c0 * 32 + pc) : (64 + c0 * 32 + (pc - 32));
      *(half8*)(khi + gbase + (size_t)row * 128 + d) = ld8h(&stH[row * 72 + pc]);
    }
  }
}

// ---------------------------------------------------------------------------
// V projection, fp16 1-pass (x hi only). Same 256x128 tiling, single phase
// per K-step (16-MFMA cluster), X 2-buffered + Wv 3-buffered (56 KB LDS,
// 2 blocks/CU), counted vmcnt(1). Epilogue writes vt = V^T directly
// ([BH][HD][T]) via LDS transpose staging.
// ---------------------------------------------------------------------------
__global__ __launch_bounds__(512, 2) void gemm_v_f16(
    const _Float16* __restrict__ xhp, const _Float16* __restrict__ wvp,
    _Float16* __restrict__ vt) {
  constexpr int Kd = 2048, NT = 64;
  const int n0 = blockIdx.x * 128, m0 = blockIdx.y * 256;
  const int tid = threadIdx.x, w = tid >> 6, lane = tid & 63;
  const int quad = lane >> 4, l16 = lane & 15;
  const int c0 = w & 1, rb = w >> 1, rgb = rb * 4;

  // LDS (halves): XH[2][8192] WV[3][4096] = 56 KB
  __shared__ __align__(16) _Float16 smem[28672];
  _Float16* XH = smem;
  _Float16* WV = smem + 16384;

  floatx4 accV[4][4];
#pragma unroll
  for (int i = 0; i < 4; i++)
#pragma unroll
    for (int c = 0; c < 4; c++) accV[i][c] = (floatx4){0.f, 0.f, 0.f, 0.f};

  const size_t xg0 = (size_t)(m0 + 32 * w + l16) * Kd + quad * 8;
  const size_t xg1 = xg0 + (size_t)16 * Kd;
  const size_t wg = (size_t)(n0 + 16 * w + l16) * Kd + quad * 8;

#define STAGE_XV(T)                                                     \
  {                                                                     \
    const int kk_ = (T) * 32;                                           \
    _Float16* bx_ = XH + ((T) & 1) * 8192;                              \
    async16(bx_ + (2 * w) * 512, xhp + xg0 + kk_);                      \
    async16(bx_ + (2 * w + 1) * 512, xhp + xg1 + kk_);                  \
  }
#define STAGE_WV(T)                                                     \
  { async16(WV + ((T) % 3) * 4096 + w * 512, wvp + wg + (T) * 32); }

  STAGE_XV(0);
  STAGE_WV(0);
  STAGE_WV(1);
  asm volatile("s_waitcnt vmcnt(1)" ::: "memory");
  __builtin_amdgcn_s_barrier();

#pragma unroll 1
  for (int t = 0; t < NT; ++t) {
    const _Float16* XH_ = XH + (t & 1) * 8192;
    const _Float16* WV_ = WV + (t % 3) * 4096;

    half8 ah[4], bv[4];
#pragma unroll
    for (int i = 0; i < 4; i++)
      ah[i] = ld8h(XH_ + (rgb + i) * 512 + lane * 8);
#pragma unroll
    for (int c = 0; c < 4; c++)
      bv[c] = ld8h(WV_ + (4 * c0 + c) * 512 + lane * 8);
    if (t + 1 < NT) STAGE_XV(t + 1);
    if (t + 2 < NT) STAGE_WV(t + 2);
    __builtin_amdgcn_s_barrier();
    asm volatile("s_waitcnt lgkmcnt(0)");
    __builtin_amdgcn_sched_barrier(0);
    __builtin_amdgcn_s_setprio(1);
#pragma unroll
    for (int i = 0; i < 4; i++)
#pragma unroll
      for (int c = 0; c < 4; c++)
        accV[i][c] = MFMA16H(ah[i], bv[c], accV[i][c]);
    __builtin_amdgcn_s_setprio(0);
    if (t + 2 < NT) {
      asm volatile("s_waitcnt vmcnt(1)" ::: "memory");
    } else {
      asm volatile("s_waitcnt vmcnt(0)" ::: "memory");
    }
    __builtin_amdgcn_s_barrier();
  }
#undef STAGE_XV
#undef STAGE_WV

  // ---- epilogue: write vt[bh][d][t] via per-wave LDS transpose staging ----
  _Float16* stV = smem + w * 1024;  // [64 d][16 t] halves per wave

  const int h = n0 >> 7;
  const int b = m0 >> 11;
  const int bh = b * 16 + h;

#pragma unroll
  for (int rg = 0; rg < 4; rg++) {
    const int tt0 = (m0 & 2047) + rb * 64 + rg * 16;
#pragma unroll
    for (int c = 0; c < 4; c++)
#pragma unroll
      for (int r = 0; r < 4; r++)
        stV[(c * 16 + l16) * 16 + quad * 4 + r] = (_Float16)accV[rg][c][r];
#pragma unroll
    for (int it = 0; it < 2; it++) {
      int dl = it * 32 + (lane >> 1), th = (lane & 1) * 8;
      int dh = c0 * 64 + dl;
      size_t ga = ((size_t)bh * 128 + dh) * 2048 + tt0 + th;
      *(half8*)(vt + ga) = ld8h(&stV[dl * 16 + th]);
    }
  }
}

// ---------------------------------------------------------------------------
// flash attention: block = (bh, 64 q-rows). 4 waves x 16 rows each -> half
// the register pressure of the 128-row block, and 1024 blocks (grid 32x32)
// so 2 blocks/CU stay resident with backfill. qt = 31 - blockIdx.y (LPT:
// longest blocks dispatch first; short ones backfill -> no causal tail).
// K-tiles of 64, K/V LDS double-buffered (73 KB). Batched shuffle softmax +
// defer-max (THR=8). setprio(1) around MFMA clusters.
// QK^T 2-pass (q split exact, k fp16-rounded), online softmax fp32, PV fp16.
// ---------------------------------------------------------------------------
__global__ __launch_bounds__(256, 2) void flash_attn(
    const _Float16* __restrict__ qhp, const _Float16* __restrict__ qlp,
    const _Float16* __restrict__ khp,
    const _Float16* __restrict__ vtp, _Float16* __restrict__ aout) {
  constexpr int T = 2048, HD = 128;
  const int bh = blockIdx.x;
  const int qt = 31 - blockIdx.y;  // LPT order
  const int q0 = qt * 64;
  const int tid = threadIdx.x, w = tid >> 6, lane = tid & 63;
  const int quad = lane >> 4, l16 = lane & 15;

  __shared__ __align__(16) _Float16 Kh[2][8192];   // 64 x 128, granule layout
  __shared__ __align__(16) _Float16 Vt[2][8192];   // 128 x 64, granule layout
  __shared__ __align__(16) _Float16 Pb[4][16 * 72];  // per-wave, padded

  const size_t qkbase = (size_t)bh * T * HD;
  const size_t vbase = (size_t)bh * HD * T;

  auto stageKV = [&](int kt, int set) {
    const int s0 = kt * 64;
    for (int c = w; c < 16; c += 4) {
      int tt = c >> 2, ss = c & 3;
      size_t go = qkbase + (size_t)(s0 + tt * 16 + l16) * HD + ss * 32 + quad * 8;
      async16(&Kh[set][c * 512], khp + go);
      int dt = c >> 1, vs = c & 1;
      size_t vo = vbase + (size_t)(dt * 16 + l16) * T + s0 + vs * 32 + quad * 8;
      async16(&Vt[set][c * 512], vtp + vo);
    }
  };

  // Q fragments: wave w owns rows [q0 + w*16, q0 + w*16 + 16)
  half8 qh[4], ql[4];
#pragma unroll
  for (int s = 0; s < 4; s++) {
    size_t off = qkbase + (size_t)(q0 + w * 16 + l16) * HD + s * 32 + quad * 8;
    qh[s] = *(const half8*)(qhp + off);
    ql[s] = *(const half8*)(qlp + off);
  }

  floatx4 o[8];
#pragma unroll
  for (int dt = 0; dt < 8; dt++) o[dt] = (floatx4){0.f, 0.f, 0.f, 0.f};
  float mrow[4], lrow[4];
#pragma unroll
  for (int r = 0; r < 4; r++) { mrow[r] = -3e38f; lrow[r] = 0.f; }

  const int ntiles = qt + 1;

  stageKV(0, 0);
  __syncthreads();

#pragma unroll 1
  for (int kt = 0; kt < ntiles; ++kt) {
    const int s0 = kt * 64;
    const int set = kt & 1;
    if (kt + 1 < ntiles) stageKV(kt + 1, set ^ 1);

    floatx4 S[4];
#pragma unroll
    for (int j = 0; j < 4; j++) S[j] = (floatx4){0.f, 0.f, 0.f, 0.f};

    __builtin_amdgcn_s_setprio(1);
#pragma unroll
    for (int s = 0; s < 4; s++) {
#pragma unroll
      for (int j = 0; j < 4; j++) {
        half8 kh = ld8h(&Kh[set][(j * 4 + s) * 512 + lane * 8]);
        S[j] = MFMA16H(qh[s], kh, S[j]);
        S[j] = MFMA16H(ql[s], kh, S[j]);
      }
    }
    __builtin_amdgcn_s_setprio(0);

    if (kt == ntiles - 1) {  // diagonal tile (s0 == q0): causal mask
      int rbase = q0 + w * 16 + quad * 4;
#pragma unroll
      for (int j = 0; j < 4; j++) {
        int cg = s0 + j * 16 + l16;
#pragma unroll
        for (int r = 0; r < 4; r++)
          if (cg > rbase + r) S[j][r] = -3e38f;
      }
    }

    // ---- softmax: batched reductions + defer-max (THR=8) ----
    float lm[4];
#pragma unroll
    for (int r = 0; r < 4; r++)
      lm[r] = fmaxf(fmaxf(S[0][r], S[1][r]), fmaxf(S[2][r], S[3][r]));

    bool ok = true;
#pragma unroll
    for (int r = 0; r < 4; r++) ok = ok && (lm[r] <= mrow[r] + 8.0f);

    if (!__all(ok ? 1 : 0)) {  // slow path: wave-uniform
#pragma unroll
      for (int d = 1; d < 16; d <<= 1)
#pragma unroll
        for (int r = 0; r < 4; r++)
          lm[r] = fmaxf(lm[r], __shfl_xor(lm[r], d, 64));
#pragma unroll
      for (int r = 0; r < 4; r++) {
        float mnew = fmaxf(mrow[r], lm[r]);
        float al = __expf(mrow[r] - mnew);
        mrow[r] = mnew;
        lrow[r] *= al;
#pragma unroll
        for (int dt = 0; dt < 8; dt++) o[dt][r] *= al;
      }
    }

    float rs[4];
#pragma unroll
    for (int r = 0; r < 4; r++) {
      float e0 = __expf(S[0][r] - mrow[r]);
      float e1 = __expf(S[1][r] - mrow[r]);
      float e2 = __expf(S[2][r] - mrow[r]);
      float e3 = __expf(S[3][r] - mrow[r]);
      S[0][r] = e0; S[1][r] = e1; S[2][r] = e2; S[3][r] = e3;
      rs[r] = (e0 + e1) + (e2 + e3);
    }
#pragma unroll
    for (int d = 1; d < 16; d <<= 1)
#pragma unroll
      for (int r = 0; r < 4; r++) rs[r] += __shfl_xor(rs[r], d, 64);
#pragma unroll
    for (int r = 0; r < 4; r++) lrow[r] += rs[r];

    // P -> LDS (A-fragment transform); per-wave buffer, DS in-order
    half8 pf[2];
#pragma unroll
    for (int r = 0; r < 4; r++)
#pragma unroll
      for (int j = 0; j < 4; j++)
        Pb[w][(quad * 4 + r) * 72 + j * 16 + l16] = (_Float16)S[j][r];
    pf[0] = ld8h(&Pb[w][l16 * 72 + quad * 8]);
    pf[1] = ld8h(&Pb[w][l16 * 72 + 32 + quad * 8]);

    __builtin_amdgcn_s_setprio(1);
#pragma unroll
    for (int dt = 0; dt < 8; dt++) {
#pragma unroll
      for (int s = 0; s < 2; s++) {
        half8 vf = ld8h(&Vt[set][(dt * 2 + s) * 512 + lane * 8]);
        o[dt] = MFMA16H(pf[s], vf, o[dt]);
      }
    }
    __builtin_amdgcn_s_setprio(0);
    __syncthreads();
  }

  const int b = bh >> 4, h = bh & 15;
#pragma unroll
  for (int r = 0; r < 4; r++) {
    int trow = q0 + w * 16 + quad * 4 + r;
    float linv = 1.0f / lrow[r];
    size_t base = ((size_t)(b * T + trow)) * 2048 + h * 128;
#pragma unroll
    for (int dt = 0; dt < 8; dt++)
      aout[base + dt * 16 + l16] = (_Float16)(o[dt][r] * linv);
  }
}

// ---------------------------------------------------------------------------
// O projection: y = aout @ Wo^T, fp16 in, fp32 out. 128x128 tile, BK=64.
// ---------------------------------------------------------------------------
__global__ __launch_bounds__(256, 2) void gemm_o_f16(
    const _Float16* __restrict__ A, const _Float16* __restrict__ B,
    float* __restrict__ outF) {
  constexpr int Kd = 2048;
  constexpr int Nd = 2048;
  const int n0 = blockIdx.x * 128, m0 = blockIdx.y * 128;
  const int tid = threadIdx.x, w = tid >> 6, lane = tid & 63;
  const int quad = lane >> 4, l16 = lane & 15;

  __shared__ __align__(16) _Float16 As[8192];  // two 32-k sub-tiles
  __shared__ __align__(16) _Float16 Bs[8192];

  floatx4 acc[2][8];
#pragma unroll
  for (int i = 0; i < 2; i++)
#pragma unroll
    for (int j = 0; j < 8; j++) acc[i][j] = (floatx4){0.f, 0.f, 0.f, 0.f};

  const int t0 = 2 * w, t1 = 2 * w + 1;
  const size_t ao0 = (size_t)(m0 + t0 * 16 + l16) * Kd + quad * 8;
  const size_t ao1 = (size_t)(m0 + t1 * 16 + l16) * Kd + quad * 8;
  const size_t bo0 = (size_t)(n0 + t0 * 16 + l16) * Kd + quad * 8;
  const size_t bo1 = (size_t)(n0 + t1 * 16 + l16) * Kd + quad * 8;

  for (int k0 = 0; k0 < Kd; k0 += 64) {
    __syncthreads();
    async16(&As[t0 * 512], A + ao0 + k0);
    async16(&As[t1 * 512], A + ao1 + k0);
    async16(&As[4096 + t0 * 512], A + ao0 + k0 + 32);
    async16(&As[4096 + t1 * 512], A + ao1 + k0 + 32);
    async16(&Bs[t0 * 512], B + bo0 + k0);
    async16(&Bs[t1 * 512], B + bo1 + k0);
    async16(&Bs[4096 + t0 * 512], B + bo0 + k0 + 32);
    async16(&Bs[4096 + t1 * 512], B + bo1 + k0 + 32);
    __syncthreads();
    half8 a00 = ld8h(&As[t0 * 512 + lane * 8]);
    half8 a10 = ld8h(&As[t1 * 512 + lane * 8]);
    half8 a01 = ld8h(&As[4096 + t0 * 512 + lane * 8]);
    half8 a11 = ld8h(&As[4096 + t1 * 512 + lane * 8]);
#pragma unroll
    for (int j = 0; j < 8; j++) {
      half8 b0 = ld8h(&Bs[j * 512 + lane * 8]);
      acc[0][j] = MFMA16H(a00, b0, acc[0][j]);
      acc[1][j] = MFMA16H(a10, b0, acc[1][j]);
      half8 b1 = ld8h(&Bs[4096 + j * 512 + lane * 8]);
      acc[0][j] = MFMA16H(a01, b1, acc[0][j]);
      acc[1][j] = MFMA16H(a11, b1, acc[1][j]);
    }
  }

#pragma unroll
  for (int i = 0; i < 2; i++) {
    int rbase = m0 + (2 * w + i) * 16 + quad * 4;
#pragma unroll
    for (int j = 0; j < 8; j++) {
      int col = n0 + j * 16 + l16;
#pragma unroll
      for (int r = 0; r < 4; r++)
        outF[(size_t)(rbase + r) * Nd + col] = acc[i][j][r];
    }
  }
}

// ---------------------------------------------------------------------------
// per-row L2 normalize: out = y / max(||y||, 1e-12)
// ---------------------------------------------------------------------------
__global__ __launch_bounds__(256) void rownorm(const float* __restrict__ y,
                                               float* __restrict__ out) {
  int row = blockIdx.x;
  const float4* yr = (const float4*)(y + (size_t)row * 2048);
  float4* od = (float4*)(out + (size_t)row * 2048);
  int t = threadIdx.x;
  float4 v0 = yr[t], v1 = yr[t + 256];
  float ss = v0.x * v0.x + v0.y * v0.y + v0.z * v0.z + v0.w * v0.w +
             v1.x * v1.x + v1.y * v1.y + v1.z * v1.z + v1.w * v1.w;
#pragma unroll
  for (int d = 1; d < 64; d <<= 1) ss += __shfl_xor(ss, d, 64);
  __shared__ float red[4];
  if ((t & 63) == 0) red[t >> 6] = ss;
  __syncthreads();
  float tot = red[0] + red[1] + red[2] + red[3];
  float inv = 1.0f / fmaxf(sqrtf(tot), 1e-12f);
  v0.x *= inv; v0.y *= inv; v0.z *= inv; v0.w *= inv;
  v1.x *= inv; v1.y *= inv; v1.z *= inv; v1.w *= inv;
  od[t] = v0;
  od[t + 256] = v1;
}

// ---------------------------------------------------------------------------
extern "C" void kernel_launch(void* const* d_in, const int* in_sizes, int n_in,
                              void* d_out, int out_size, void* d_ws, size_t ws_size,
                              hipStream_t stream) {
  (void)in_sizes; (void)n_in; (void)out_size; (void)ws_size;
  const float* x   = (const float*)d_in[0];
  const float* Wq  = (const float*)d_in[1];
  const float* Wk  = (const float*)d_in[2];
  const float* Wv  = (const float*)d_in[3];
  const float* Wo  = (const float*)d_in[4];
  const float* sqk = (const float*)d_in[5];
  char* ws = (char*)d_ws;

  constexpr size_t SZX = 8388608ull * 2;  // fp16 x-sized buffer (16 MB)
  constexpr size_t SZW = 4194304ull * 2;  // fp16 weight buffer (8 MB)

  size_t o_xh = 0;
  size_t o_xl = o_xh + SZX;
  size_t o_wq = o_xl + SZX;
  size_t o_wk = o_wq + SZW;
  size_t o_wv = o_wk + SZW;
  size_t o_wo = o_wv + SZW;
  size_t o_qh = o_wo + SZW;
  size_t o_ql = o_qh + SZX;
  size_t o_kh = o_ql + SZX;
  size_t o_v  = o_kh + SZX;
  size_t o_vt = o_v + SZX;
  size_t o_cos = o_vt + SZX;
  size_t o_sin = o_cos + 2048 * 64 * 4;
  // aliases (lifetimes disjoint):
  size_t o_aout = o_wq;  // 16 MB over wq+wk (dead after QK proj)
  size_t o_y    = o_qh;  // 32 MB fp32 over qh+ql (dead after flash)

  _Float16* xh = (_Float16*)(ws + o_xh);
  _Float16* xl = (_Float16*)(ws + o_xl);
  _Float16* wq = (_Float16*)(ws + o_wq);
  _Float16* wk = (_Float16*)(ws + o_wk);
  _Float16* wv = (_Float16*)(ws + o_wv);
  _Float16* wo = (_Float16*)(ws + o_wo);
  _Float16* qh = (_Float16*)(ws + o_qh);
  _Float16* ql = (_Float16*)(ws + o_ql);
  _Float16* kh = (_Float16*)(ws + o_kh);
  _Float16* vt = (_Float16*)(ws + o_vt);
  float* cosT = (float*)(ws + o_cos);
  float* sinT = (float*)(ws + o_sin);
  _Float16* aout = (_Float16*)(ws + o_aout);
  float* y = (float*)(ws + o_y);

  cvt_prep<<<8192, 256, 0, stream>>>((const float4*)x, (const float4*)Wq,
                                     (const float4*)Wk, (const float4*)Wv,
                                     (const float4*)Wo, (half4v*)xh, (half4v*)xl,
                                     (half4v*)wq, (half4v*)wk, (half4v*)wv,
                                     (half4v*)wo, cosT, sinT);

  gemm_qk_f16<<<dim3(16, 16), 512, 0, stream>>>(xh, xl, wq, wk, cosT, sinT,
                                                sqk, qh, ql, kh);
  gemm_v_f16<<<dim3(16, 16), 512, 0, stream>>>(xh, wv, vt);

  flash_attn<<<dim3(32, 32), 256, 0, stream>>>(qh, ql, kh, vt, aout);

  gemm_o_f16<<<dim3(16, 32), 256, 0, stream>>>(aout, wo, y);
  rownorm<<<4096, 256, 0, stream>>>(y, (float*)d_out);
}